// Round 13
// baseline (265.288 us; speedup 1.0000x reference)
//
#include <hip/hip_runtime.h>

#define BSZ 256
#define NND 22
#define BN_EPS 1e-5f

// ---------------------------------------------------------------------------
// conv core for CIN<=4 (used by S1 only). c-loop unroll-1 ON PURPOSE
// (R4-R7 lesson): full unroll at CIN>=4 blows VGPR to 164-256.
// ---------------------------------------------------------------------------
template<int CIN, int COUT, int R, int SROW>
__device__ __forceinline__ void conv_coreR(
    const float (*s_in)[SROW], const float* s_w, int tid, float y[COUT][R]) {
#pragma unroll
  for (int o = 0; o < COUT; o++)
#pragma unroll
    for (int r = 0; r < R; r++) y[o][r] = 0.f;
#pragma unroll 1
  for (int c = 0; c < CIN; c++) {
    float xr[R + 6];
    if constexpr (R == 4) {
      const float4* xp = (const float4*)&s_in[c][4 * tid];
      float4 xa = xp[0], xb = xp[1];
      float2 xc = *(const float2*)&s_in[c][4 * tid + 8];
      xr[0] = xa.x; xr[1] = xa.y; xr[2] = xa.z; xr[3] = xa.w;
      xr[4] = xb.x; xr[5] = xb.y; xr[6] = xb.z; xr[7] = xb.w;
      xr[8] = xc.x; xr[9] = xc.y;
    } else {
      const float2* xp = (const float2*)&s_in[c][2 * tid];
      float2 x0 = xp[0], x1 = xp[1], x2 = xp[2], x3 = xp[3];
      xr[0] = x0.x; xr[1] = x0.y; xr[2] = x1.x; xr[3] = x1.y;
      xr[4] = x2.x; xr[5] = x2.y; xr[6] = x3.x; xr[7] = x3.y;
    }
#pragma unroll
    for (int k = 0; k < 7; k++) {
      const float4* wp = (const float4*)&s_w[(c * 7 + k) * COUT];
#pragma unroll
      for (int o4 = 0; o4 < COUT / 4; o4++) {
        float4 wv = wp[o4];
#pragma unroll
        for (int r = 0; r < R; r++) {
          y[4 * o4 + 0][r] += wv.x * xr[r + k];
          y[4 * o4 + 1][r] += wv.y * xr[r + k];
          y[4 * o4 + 2][r] += wv.z * xr[r + k];
          y[4 * o4 + 3][r] += wv.w * xr[r + k];
        }
      }
    }
  }
}

template<int CIN, int COUT, int NTH>
__device__ __forceinline__ void stage_weights(const float* __restrict__ w,
                                              float* s_w, int tid) {
  for (int i = tid; i < CIN * 7 * COUT; i += NTH) {
    int c = i / (7 * COUT), k = (i / COUT) % 7, o = i % COUT;
    s_w[i] = w[(o * CIN + c) * 7 + k];
  }
}

// ---------------------------------------------------------------------------
// S1: stats of conv1 over x -> private partial slot. Block (0,0,0) also
// pre-transposes conv2/conv3 weights to [c][k][o] (folded prep launch).
// grid: (2, BSZ, NND), block 256.
// ---------------------------------------------------------------------------
template<int CIN, int COUT, int LIN, int NTH, int NT, int R>
__global__ __launch_bounds__(NTH) void conv_statsR(
    const float* __restrict__ in, long sn, long sb, long sc,
    const float* __restrict__ w, float* __restrict__ part,
    const float* __restrict__ w2, const float* __restrict__ w3,
    float* __restrict__ w2t, float* __restrict__ w3t) {
  const int TILE = R * NTH;
  const int SROW = TILE + 8;
  __shared__ alignas(16) float s_in[CIN][SROW];
  __shared__ alignas(16) float s_w[CIN * 7 * COUT];
  __shared__ float s_red[2][NTH / 64][COUT];
  int tid = threadIdx.x, n = blockIdx.z, b = blockIdx.y;
  if (blockIdx.x == 0 && b == 0 && n == 0) {   // folded prep_weights
    if (tid < 224) {
      int c = tid / 56, k = (tid / 8) % 7, o = tid & 7;
      w2t[tid] = w2[(o * 4 + c) * 7 + k];
    }
    for (int i = tid; i < 896; i += NTH) {
      int c = i / 112, k = (i / 16) % 7, o = i & 15;
      w3t[i] = w3[(o * 8 + c) * 7 + k];
    }
  }
  int t0 = blockIdx.x * TILE;
  const float* base = in + (long)n * sn + (long)b * sb;
  stage_weights<CIN, COUT, NTH>(w, s_w, tid);
  for (int c = 0; c < CIN; c++)
    for (int i = tid; i < TILE + 6; i += NTH) {
      int l = t0 + i - 3;
      s_in[c][i] = (l >= 0 && l < LIN) ? base[(long)c * sc + l] : 0.f;
    }
  __syncthreads();
  float y[COUT][R];
  conv_coreR<CIN, COUT, R, SROW>(s_in, s_w, tid, y);
  bool valid = (t0 + R * tid) < LIN;
  int lane = tid & 63, wv = tid >> 6;
#pragma unroll
  for (int o = 0; o < COUT; o++) {
    float s = 0.f, q = 0.f;
    if (valid) {
#pragma unroll
      for (int r = 0; r < R; r++) { s += y[o][r]; q += y[o][r] * y[o][r]; }
    }
#pragma unroll
    for (int off = 32; off > 0; off >>= 1) {
      s += __shfl_down(s, off, 64);
      q += __shfl_down(q, off, 64);
    }
    if (lane == 0) { s_red[0][wv][o] = s; s_red[1][wv][o] = q; }
  }
  __syncthreads();
  if (tid < COUT) {
    float s = 0.f, q = 0.f;
#pragma unroll
    for (int g = 0; g < NTH / 64; g++) { s += s_red[0][g][tid]; q += s_red[1][g][tid]; }
    long slot = ((long)n * NT + blockIdx.x) * BSZ + b;
    part[slot * (2 * COUT) + tid] = s;
    part[slot * (2 * COUT) + COUT + tid] = q;
  }
}

// ---------------------------------------------------------------------------
// F1: in-block scs1 (from p1 partials, L2-resident) -> conv1+BN1+ReLU+pool
// -> h1 (LDS ONLY) -> conv2 -> pooled raw conv2 to global (y2p; scale2>0 so
// maxpool∘relu∘BN == relu∘BN∘maxpool) + stats2 partials.
// grid: (1, B, N), block 256.
// ---------------------------------------------------------------------------
__global__ __launch_bounds__(256) void fused1(
    const float* __restrict__ x,      // (B, N, 2000)
    const float* __restrict__ w1,     // (4,1,7)
    const float* __restrict__ p1,     // stats1 partials: node n slots n*512..
    const float* __restrict__ g1, const float* __restrict__ b1,
    const float* __restrict__ w2t,    // [c][k][o] transposed conv2 weights
    float* __restrict__ y2p,          // [n][b][8][500] pooled raw conv2
    float* __restrict__ p2) {         // [(n*256+b)*16]
  __shared__ alignas(16) float s_x[2016];       // s_x[j+4] = x[j]
  __shared__ alignas(16) float s_h1[5][1008];   // row 4 = garbage prefetch row
  __shared__ float s_scred[4][8];
  __shared__ float s_sc[4], s_sh[4];
  __shared__ float s_red[2][4][8];
  int tid = threadIdx.x, n = blockIdx.z, b = blockIdx.y;
  int lane = tid & 63, wv = tid >> 6;
  const float* xb = x + (long)b * (NND * 2000) + (long)n * 2000;
  {  // stage x (issue loads early) + scs1 butterfly in parallel
    float4 a0 = *(const float4*)&xb[4 * tid];
    float4 a1;
    bool m1 = tid + 256 < 500;
    if (m1) a1 = *(const float4*)&xb[4 * (tid + 256)];
    // in-block scs1: thread t sums slots t and t+256 of node n (8 floats each)
    const float* pp = p1 + (long)n * 512 * 8;
    float v[8];
    {
      float4 u0 = *(const float4*)&pp[tid * 8];
      float4 u1 = *(const float4*)&pp[tid * 8 + 4];
      float4 u2 = *(const float4*)&pp[(tid + 256) * 8];
      float4 u3 = *(const float4*)&pp[(tid + 256) * 8 + 4];
      v[0] = u0.x + u2.x; v[1] = u0.y + u2.y; v[2] = u0.z + u2.z; v[3] = u0.w + u2.w;
      v[4] = u1.x + u3.x; v[5] = u1.y + u3.y; v[6] = u1.z + u3.z; v[7] = u1.w + u3.w;
    }
#pragma unroll
    for (int off = 32; off > 0; off >>= 1)
#pragma unroll
      for (int j = 0; j < 8; j++) v[j] += __shfl_down(v[j], off, 64);
    if (lane == 0)
#pragma unroll
      for (int j = 0; j < 8; j++) s_scred[wv][j] = v[j];
    *(float4*)&s_x[4 * tid + 4] = a0;
    if (m1) *(float4*)&s_x[4 * (tid + 256) + 4] = a1;
    if (tid == 0) {
      *(float4*)&s_x[0] = make_float4(0.f, 0.f, 0.f, 0.f);
      *(float4*)&s_x[2004] = make_float4(0.f, 0.f, 0.f, 0.f);
    }
  }
  __syncthreads();
  if (tid < 4) {
    float S = 0.f, Q = 0.f;
#pragma unroll
    for (int g = 0; g < 4; g++) { S += s_scred[g][tid]; Q += s_scred[g][tid + 4]; }
    float cnt = 256.f * 2000.f;
    float m = S / cnt, var = Q / cnt - m * m;
    float istd = 1.0f / sqrtf(var + BN_EPS);
    float scl = g1[tid] * istd;
    s_sc[tid] = scl;
    s_sh[tid] = b1[tid] - m * scl;
  }
  __syncthreads();
  // ---- Phase A: conv1 (8 pos/thread) + BN1 + ReLU + pool -> s_h1 ----
  if (tid < 250) {                                  // 8*250 = 2000 exactly
    float xr[16];
    const float4* xp = (const float4*)&s_x[8 * tid];
#pragma unroll
    for (int v2 = 0; v2 < 4; v2++) {
      float4 t = xp[v2];
      xr[4 * v2 + 0] = t.x; xr[4 * v2 + 1] = t.y;
      xr[4 * v2 + 2] = t.z; xr[4 * v2 + 3] = t.w;
    }
    float y[4][8];
#pragma unroll
    for (int o = 0; o < 4; o++)
#pragma unroll
      for (int r = 0; r < 8; r++) y[o][r] = 0.f;
#pragma unroll
    for (int k = 0; k < 7; k++) {
      float w0 = w1[0 * 7 + k], w1v = w1[1 * 7 + k];
      float w2v = w1[2 * 7 + k], w3v = w1[3 * 7 + k];
#pragma unroll
      for (int r = 0; r < 8; r++) {
        y[0][r] += w0 * xr[r + k + 1];
        y[1][r] += w1v * xr[r + k + 1];
        y[2][r] += w2v * xr[r + k + 1];
        y[3][r] += w3v * xr[r + k + 1];
      }
    }
#pragma unroll
    for (int o = 0; o < 4; o++) {
      float a0 = y[o][0] * s_sc[o] + s_sh[o], a1 = y[o][1] * s_sc[o] + s_sh[o];
      float a2 = y[o][2] * s_sc[o] + s_sh[o], a3 = y[o][3] * s_sc[o] + s_sh[o];
      float a4 = y[o][4] * s_sc[o] + s_sh[o], a5 = y[o][5] * s_sc[o] + s_sh[o];
      float a6 = y[o][6] * s_sc[o] + s_sh[o], a7 = y[o][7] * s_sc[o] + s_sh[o];
      float4 v2;
      v2.x = fmaxf(fmaxf(a0, a1), 0.f);
      v2.y = fmaxf(fmaxf(a2, a3), 0.f);
      v2.z = fmaxf(fmaxf(a4, a5), 0.f);
      v2.w = fmaxf(fmaxf(a6, a7), 0.f);
      *(float4*)&s_h1[o][4 * tid + 4] = v2;     // 16B-aligned, conflict-free
    }
  }
  if (tid < 4) {
    *(float4*)&s_h1[tid][0] = make_float4(0.f, 0.f, 0.f, 0.f);
    *(float4*)&s_h1[tid][1004] = make_float4(0.f, 0.f, 0.f, 0.f);
  }
  __syncthreads();
  // ---- Phase B: conv2 (pipelined x-reads) -> stats2 + pooled raw y2p ----
  float y2[8][4];
#pragma unroll
  for (int o = 0; o < 8; o++)
#pragma unroll
    for (int r = 0; r < 4; r++) y2[o][r] = 0.f;
  if (tid < 250) {                                  // 4*250 = 1000 exactly
    const float4* xp0 = (const float4*)&s_h1[0][4 * tid];
    float4 n0 = xp0[0], n1 = xp0[1], n2 = xp0[2];
#pragma unroll 1
    for (int c = 0; c < 4; c++) {
      float4 c0 = n0, c1 = n1, c2 = n2;
      const float4* xpn = (const float4*)&s_h1[c + 1][4 * tid];  // row4 garbage ok
      n0 = xpn[0]; n1 = xpn[1]; n2 = xpn[2];
      float xr[12];
      xr[0] = c0.x; xr[1] = c0.y; xr[2] = c0.z; xr[3] = c0.w;
      xr[4] = c1.x; xr[5] = c1.y; xr[6] = c1.z; xr[7] = c1.w;
      xr[8] = c2.x; xr[9] = c2.y; xr[10] = c2.z; xr[11] = c2.w;
#pragma unroll
      for (int k = 0; k < 7; k++) {
        float4 w0 = *(const float4*)&w2t[(c * 7 + k) * 8];       // s_load
        float4 w1v = *(const float4*)&w2t[(c * 7 + k) * 8 + 4];
#pragma unroll
        for (int r = 0; r < 4; r++) {
          float xv = xr[r + k + 1];
          y2[0][r] += w0.x * xv;
          y2[1][r] += w0.y * xv;
          y2[2][r] += w0.z * xv;
          y2[3][r] += w0.w * xv;
          y2[4][r] += w1v.x * xv;
          y2[5][r] += w1v.y * xv;
          y2[6][r] += w1v.z * xv;
          y2[7][r] += w1v.w * xv;
        }
      }
    }
    long yb = ((long)n * BSZ + b) * 4000 + 2 * tid;
#pragma unroll
    for (int o = 0; o < 8; o++) {
      float2 v2;
      v2.x = fmaxf(y2[o][0], y2[o][1]);
      v2.y = fmaxf(y2[o][2], y2[o][3]);
      *(float2*)&y2p[yb + o * 500] = v2;
    }
  }
#pragma unroll
  for (int o = 0; o < 8; o++) {
    float s = y2[o][0] + y2[o][1] + y2[o][2] + y2[o][3];
    float q = y2[o][0] * y2[o][0] + y2[o][1] * y2[o][1] +
              y2[o][2] * y2[o][2] + y2[o][3] * y2[o][3];
#pragma unroll
    for (int off = 32; off > 0; off >>= 1) {
      s += __shfl_down(s, off, 64);
      q += __shfl_down(q, off, 64);
    }
    if (lane == 0) { s_red[0][wv][o] = s; s_red[1][wv][o] = q; }
  }
  __syncthreads();
  if (tid < 8) {
    float s = 0.f, q = 0.f;
#pragma unroll
    for (int g = 0; g < 4; g++) { s += s_red[0][g][tid]; q += s_red[1][g][tid]; }
    long slot = (long)n * BSZ + b;
    p2[slot * 16 + tid] = s;
    p2[slot * 16 + 8 + tid] = q;
  }
}

// ---------------------------------------------------------------------------
// F2: in-block scs2 (from p2, L2-resident) -> BN2+ReLU on y2p -> h2 in LDS,
// conv3 (channel-split, pipelined x-reads) -> pooled raw conv3 (y3p) +
// stats3 partials. grid: (1, B, N), block 256.
// ---------------------------------------------------------------------------
__global__ __launch_bounds__(256) void fused2(
    const float* __restrict__ y2p,    // [n][b][8][500]
    const float* __restrict__ p2,
    const float* __restrict__ g2, const float* __restrict__ b2,
    const float* __restrict__ w3t,    // [c][k][o] transposed conv3 weights
    float* __restrict__ y3p,          // [n][b][16][250] pooled raw conv3
    float* __restrict__ p3) {         // [(n*256+b)*32]
  __shared__ alignas(16) float s_h2[9][512];    // row 8 = garbage prefetch row
  __shared__ float s_scred[4][16];
  __shared__ float s_sc[8], s_sh[8];
  __shared__ float s_red[2][4][8];
  int tid = threadIdx.x, n = blockIdx.z, b = blockIdx.y;
  int lane = tid & 63, wv = tid >> 6;
  const float* yb2 = y2p + ((long)n * BSZ + b) * 4000;
  // issue the 4 staging loads early; scs2 butterfly hides their latency
  int i0 = tid, i1 = tid + 256, i2 = tid + 512, i3 = tid + 768;
  int c0 = i0 / 125, j0 = i0 % 125;
  int c1 = i1 / 125, j1 = i1 % 125;
  int c2 = i2 / 125, j2 = i2 % 125;
  int c3 = i3 / 125, j3 = i3 % 125;
  bool m3 = i3 < 1000;
  float4 a0 = *(const float4*)&yb2[c0 * 500 + 4 * j0];
  float4 a1 = *(const float4*)&yb2[c1 * 500 + 4 * j1];
  float4 a2 = *(const float4*)&yb2[c2 * 500 + 4 * j2];
  float4 a3;
  if (m3) a3 = *(const float4*)&yb2[c3 * 500 + 4 * j3];
  {  // in-block scs2: thread t reads slot n*256+t (16 floats)
    const float* pp = p2 + (long)n * 256 * 16;
    float v[16];
#pragma unroll
    for (int q = 0; q < 4; q++) {
      float4 u = *(const float4*)&pp[tid * 16 + 4 * q];
      v[4 * q + 0] = u.x; v[4 * q + 1] = u.y; v[4 * q + 2] = u.z; v[4 * q + 3] = u.w;
    }
#pragma unroll
    for (int off = 32; off > 0; off >>= 1)
#pragma unroll
      for (int j = 0; j < 16; j++) v[j] += __shfl_down(v[j], off, 64);
    if (lane == 0)
#pragma unroll
      for (int j = 0; j < 16; j++) s_scred[wv][j] = v[j];
  }
  __syncthreads();
  if (tid < 8) {
    float S = 0.f, Q = 0.f;
#pragma unroll
    for (int g = 0; g < 4; g++) { S += s_scred[g][tid]; Q += s_scred[g][tid + 8]; }
    float cnt = 256.f * 1000.f;
    float m = S / cnt, var = Q / cnt - m * m;
    float istd = 1.0f / sqrtf(var + BN_EPS);
    float scl = g2[tid] * istd;
    s_sc[tid] = scl;
    s_sh[tid] = b2[tid] - m * scl;
  }
  __syncthreads();
  {  // BN2 + ReLU -> s_h2 (b128 aligned writes, conflict-free)
    float sc, sh;
    sc = s_sc[c0]; sh = s_sh[c0];
    a0.x = fmaxf(a0.x * sc + sh, 0.f); a0.y = fmaxf(a0.y * sc + sh, 0.f);
    a0.z = fmaxf(a0.z * sc + sh, 0.f); a0.w = fmaxf(a0.w * sc + sh, 0.f);
    *(float4*)&s_h2[c0][4 * j0 + 4] = a0;
    sc = s_sc[c1]; sh = s_sh[c1];
    a1.x = fmaxf(a1.x * sc + sh, 0.f); a1.y = fmaxf(a1.y * sc + sh, 0.f);
    a1.z = fmaxf(a1.z * sc + sh, 0.f); a1.w = fmaxf(a1.w * sc + sh, 0.f);
    *(float4*)&s_h2[c1][4 * j1 + 4] = a1;
    sc = s_sc[c2]; sh = s_sh[c2];
    a2.x = fmaxf(a2.x * sc + sh, 0.f); a2.y = fmaxf(a2.y * sc + sh, 0.f);
    a2.z = fmaxf(a2.z * sc + sh, 0.f); a2.w = fmaxf(a2.w * sc + sh, 0.f);
    *(float4*)&s_h2[c2][4 * j2 + 4] = a2;
    if (m3) {
      sc = s_sc[c3]; sh = s_sh[c3];
      a3.x = fmaxf(a3.x * sc + sh, 0.f); a3.y = fmaxf(a3.y * sc + sh, 0.f);
      a3.z = fmaxf(a3.z * sc + sh, 0.f); a3.w = fmaxf(a3.w * sc + sh, 0.f);
      *(float4*)&s_h2[c3][4 * j3 + 4] = a3;
    }
  }
  if (tid < 8) {
    *(float4*)&s_h2[tid][0] = make_float4(0.f, 0.f, 0.f, 0.f);
    *(float4*)&s_h2[tid][504] = make_float4(0.f, 0.f, 0.f, 0.f);
  }
  __syncthreads();
  // conv3 channel-split over in-LDS h2; pipelined x-reads; SGPR weights
  int og = __builtin_amdgcn_readfirstlane(tid >> 7);  // wave-uniform
  int pt = tid & 127;
  bool valid = pt < 125;                            // 4*125 = 500 exactly
  float y3[8][4];
#pragma unroll
  for (int o = 0; o < 8; o++)
#pragma unroll
    for (int r = 0; r < 4; r++) y3[o][r] = 0.f;
  if (valid) {
    const float4* xp0 = (const float4*)&s_h2[0][4 * pt];
    float4 n0 = xp0[0], n1 = xp0[1], n2 = xp0[2];
#pragma unroll 1
    for (int c = 0; c < 8; c++) {
      float4 d0 = n0, d1 = n1, d2 = n2;
      const float4* xpn = (const float4*)&s_h2[c + 1][4 * pt];  // row8 garbage ok
      n0 = xpn[0]; n1 = xpn[1]; n2 = xpn[2];
      float xr[12];
      xr[0] = d0.x; xr[1] = d0.y; xr[2] = d0.z; xr[3] = d0.w;
      xr[4] = d1.x; xr[5] = d1.y; xr[6] = d1.z; xr[7] = d1.w;
      xr[8] = d2.x; xr[9] = d2.y; xr[10] = d2.z; xr[11] = d2.w;
#pragma unroll
      for (int k = 0; k < 7; k++) {
        float4 w0 = *(const float4*)&w3t[(c * 7 + k) * 16 + og * 8];
        float4 w1v = *(const float4*)&w3t[(c * 7 + k) * 16 + og * 8 + 4];
#pragma unroll
        for (int r = 0; r < 4; r++) {
          float xv = xr[r + k + 1];
          y3[0][r] += w0.x * xv;
          y3[1][r] += w0.y * xv;
          y3[2][r] += w0.z * xv;
          y3[3][r] += w0.w * xv;
          y3[4][r] += w1v.x * xv;
          y3[5][r] += w1v.y * xv;
          y3[6][r] += w1v.z * xv;
          y3[7][r] += w1v.w * xv;
        }
      }
    }
    long yb = (((long)n * BSZ + b) * 16 + og * 8) * 250 + 2 * pt;
#pragma unroll
    for (int o = 0; o < 8; o++) {
      float2 v2;
      v2.x = fmaxf(y3[o][0], y3[o][1]);
      v2.y = fmaxf(y3[o][2], y3[o][3]);
      *(float2*)&y3p[yb + o * 250] = v2;
    }
  }
#pragma unroll
  for (int o = 0; o < 8; o++) {
    float s = y3[o][0] + y3[o][1] + y3[o][2] + y3[o][3];
    float q = y3[o][0] * y3[o][0] + y3[o][1] * y3[o][1] +
              y3[o][2] * y3[o][2] + y3[o][3] * y3[o][3];
#pragma unroll
    for (int off = 32; off > 0; off >>= 1) {
      s += __shfl_down(s, off, 64);
      q += __shfl_down(q, off, 64);
    }
    if (lane == 0) { s_red[0][wv][o] = s; s_red[1][wv][o] = q; }
  }
  __syncthreads();
  if (tid < 16) {
    int og2 = tid >> 3, o = tid & 7;
    float s = s_red[0][2 * og2][o] + s_red[0][2 * og2 + 1][o];
    float q = s_red[1][2 * og2][o] + s_red[1][2 * og2 + 1][o];
    long slot = (long)n * BSZ + b;
    p3[slot * 32 + tid] = s;
    p3[slot * 32 + 16 + tid] = q;
  }
}

// ---------------------------------------------------------------------------
// F3: in-block scs3 (from p3) -> BN3 + ReLU + avg over pooled raw conv3
// -> feat[b][n][16]. grid: (1, B, N), block 256 (16 chans x 16 threads).
// ---------------------------------------------------------------------------
__global__ __launch_bounds__(256) void feat_apply(
    const float* __restrict__ y3p,
    const float* __restrict__ p3,
    const float* __restrict__ g3, const float* __restrict__ b3,
    float* __restrict__ feat) {
  __shared__ float s_scred[4][32];
  __shared__ float s_sc[16], s_sh[16];
  int tid = threadIdx.x, n = blockIdx.z, b = blockIdx.y;
  int lane = tid & 63, wv = tid >> 6;
  {  // in-block scs3: thread t reads slot n*256+t (32 floats)
    const float* pp = p3 + (long)n * 256 * 32;
    float v[32];
#pragma unroll
    for (int q = 0; q < 8; q++) {
      float4 u = *(const float4*)&pp[tid * 32 + 4 * q];
      v[4 * q + 0] = u.x; v[4 * q + 1] = u.y; v[4 * q + 2] = u.z; v[4 * q + 3] = u.w;
    }
#pragma unroll
    for (int off = 32; off > 0; off >>= 1)
#pragma unroll
      for (int j = 0; j < 32; j++) v[j] += __shfl_down(v[j], off, 64);
    if (lane == 0)
#pragma unroll
      for (int j = 0; j < 32; j++) s_scred[wv][j] = v[j];
  }
  __syncthreads();
  if (tid < 16) {
    float S = 0.f, Q = 0.f;
#pragma unroll
    for (int g = 0; g < 4; g++) { S += s_scred[g][tid]; Q += s_scred[g][tid + 16]; }
    float cnt = 256.f * 500.f;
    float m = S / cnt, var = Q / cnt - m * m;
    float istd = 1.0f / sqrtf(var + BN_EPS);
    float scl = g3[tid] * istd;
    s_sc[tid] = scl;
    s_sh[tid] = b3[tid] - m * scl;
  }
  __syncthreads();
  int ch = tid >> 4, s = tid & 15;
  const float* yb = y3p + (((long)n * BSZ + b) * 16 + ch) * 250;
  float sc = s_sc[ch], sh = s_sh[ch];
  float acc = 0.f;
  for (int j = s; j < 125; j += 16) {
    float2 v = *(const float2*)&yb[2 * j];
    acc += fmaxf(v.x * sc + sh, 0.f) + fmaxf(v.y * sc + sh, 0.f);
  }
#pragma unroll
  for (int off = 8; off > 0; off >>= 1) acc += __shfl_down(acc, off, 16);
  if (s == 0) feat[((long)b * NND + n) * 16 + ch] = acc * (1.0f / 250.f);
}

// ---------------------------------------------------------------------------
// Graph tail: adjacency (top-4 incl self) + 3 GCN layers + node-mean + MLP
// grid: (B), block: 256. (Separate from feat: R12 lesson — folding feat's
// 90 MB read into 256 blocks was latency-bound, +30us.)
// ---------------------------------------------------------------------------
__global__ __launch_bounds__(256) void graph_head(
    const float* __restrict__ feat,
    const float* __restrict__ gw1, const float* __restrict__ gb1,
    const float* __restrict__ gw2, const float* __restrict__ gb2,
    const float* __restrict__ gw3, const float* __restrict__ gb3,
    const float* __restrict__ fw1, const float* __restrict__ fb1,
    const float* __restrict__ fw2, const float* __restrict__ fb2,
    float* __restrict__ out) {
  int b = blockIdx.x, tid = threadIdx.x;
  __shared__ float s_feat[NND][16];
  __shared__ float s_sq[NND];
  __shared__ float s_dist[NND][NND];
  __shared__ float s_adj[NND][NND];
  __shared__ float s_x[NND][128];
  __shared__ float s_t[NND][128];
  __shared__ float s_pool[128];
  __shared__ float s_h[64];
  for (int i = tid; i < NND * 16; i += 256) s_feat[i >> 4][i & 15] = feat[b * NND * 16 + i];
  __syncthreads();
  if (tid < NND) {
    float s = 0.f;
    for (int c = 0; c < 16; c++) s += s_feat[tid][c] * s_feat[tid][c];
    s_sq[tid] = s;
  }
  __syncthreads();
  for (int i = tid; i < NND * NND; i += 256) {
    int nn = i / NND, m = i % NND;
    float d = 0.f;
    for (int c = 0; c < 16; c++) d += s_feat[nn][c] * s_feat[m][c];
    s_dist[nn][m] = s_sq[nn] + s_sq[m] - 2.f * d;  // diagonal exactly 0
    s_adj[nn][m] = 0.f;
  }
  __syncthreads();
  if (tid < NND) {  // top-4 smallest, ties -> earliest index (matches top_k)
    unsigned used = 0;
    for (int j = 0; j < 4; j++) {
      float best = 3.4e38f; int bi = 0;
      for (int m = 0; m < NND; m++)
        if (!((used >> m) & 1u) && s_dist[tid][m] < best) { best = s_dist[tid][m]; bi = m; }
      used |= 1u << bi;
      s_adj[tid][bi] = 0.25f;
    }
  }
  __syncthreads();
  for (int i = tid; i < NND * 32; i += 256) {
    int nn = i / 32, f = i % 32;
    float a = 0.f;
    for (int c = 0; c < 16; c++) a += s_feat[nn][c] * gw1[c * 32 + f];
    s_t[nn][f] = a;
  }
  __syncthreads();
  for (int i = tid; i < NND * 32; i += 256) {
    int nn = i / 32, f = i % 32;
    float a = gb1[f];
    for (int m = 0; m < NND; m++) a += s_adj[nn][m] * s_t[m][f];
    s_x[nn][f] = fmaxf(a, 0.f);
  }
  __syncthreads();
  for (int i = tid; i < NND * 64; i += 256) {
    int nn = i / 64, f = i % 64;
    float a = 0.f;
    for (int c = 0; c < 32; c++) a += s_x[nn][c] * gw2[c * 64 + f];
    s_t[nn][f] = a;
  }
  __syncthreads();
  for (int i = tid; i < NND * 64; i += 256) {
    int nn = i / 64, f = i % 64;
    float a = gb2[f];
    for (int m = 0; m < NND; m++) a += s_adj[nn][m] * s_t[m][f];
    s_x[nn][f] = fmaxf(a, 0.f);
  }
  __syncthreads();
  for (int i = tid; i < NND * 128; i += 256) {
    int nn = i / 128, f = i % 128;
    float a = 0.f;
    for (int c = 0; c < 64; c++) a += s_x[nn][c] * gw3[c * 128 + f];
    s_t[nn][f] = a;
  }
  __syncthreads();
  for (int i = tid; i < NND * 128; i += 256) {
    int nn = i / 128, f = i % 128;
    float a = gb3[f];
    for (int m = 0; m < NND; m++) a += s_adj[nn][m] * s_t[m][f];
    s_x[nn][f] = fmaxf(a, 0.f);
  }
  __syncthreads();
  if (tid < 128) {
    float a = 0.f;
    for (int m = 0; m < NND; m++) a += s_x[m][tid];
    s_pool[tid] = a * (1.0f / (float)NND);
  }
  __syncthreads();
  if (tid < 64) {
    float a = fb1[tid];
    for (int c = 0; c < 128; c++) a += s_pool[c] * fw1[c * 64 + tid];
    s_h[tid] = a;
  }
  __syncthreads();
  if (tid < 4) {
    float a = fb2[tid];
    for (int c = 0; c < 64; c++) a += s_h[c] * fw2[c * 4 + tid];
    out[b * 4 + tid] = a;
  }
}

extern "C" void kernel_launch(void* const* d_in, const int* in_sizes, int n_in,
                              void* d_out, int out_size, void* d_ws, size_t ws_size,
                              hipStream_t stream) {
  (void)in_sizes; (void)n_in; (void)out_size; (void)ws_size;
  const float* x   = (const float*)d_in[0];
  const float* w1  = (const float*)d_in[1];
  const float* g1  = (const float*)d_in[2];
  const float* b1  = (const float*)d_in[3];
  const float* w2  = (const float*)d_in[4];
  const float* g2  = (const float*)d_in[5];
  const float* b2  = (const float*)d_in[6];
  const float* w3  = (const float*)d_in[7];
  const float* g3  = (const float*)d_in[8];
  const float* b3  = (const float*)d_in[9];
  const float* gw1 = (const float*)d_in[10];
  const float* gb1 = (const float*)d_in[11];
  const float* gw2 = (const float*)d_in[12];
  const float* gb2 = (const float*)d_in[13];
  const float* gw3 = (const float*)d_in[14];
  const float* gb3 = (const float*)d_in[15];
  const float* fw1 = (const float*)d_in[16];
  const float* fb1 = (const float*)d_in[17];
  const float* fw2 = (const float*)d_in[18];
  const float* fb2 = (const float*)d_in[19];

  float* ws = (float*)d_ws;
  const long Y2 = (long)NND * BSZ * 8 * 500;    // 22,528,000 floats
  const long Y3 = (long)NND * BSZ * 16 * 250;   // 22,528,000 floats
  float* y2p  = ws;
  float* y3p  = y2p + Y2;
  float* feat = y3p + Y3;                       // B*N*16 = 90,112
  float* p1   = feat + (long)BSZ * NND * 16;    // 22*512 slots * 8
  float* p2   = p1 + (long)NND * 512 * 8;       // 22*256 slots * 16
  float* p3   = p2 + (long)NND * 256 * 16;      // 22*256 slots * 32
  float* w2t  = p3 + (long)NND * 256 * 32;      // 224
  float* w3t  = w2t + 224;                      // 896
  // total ws ~= 181 MB (same budget as prior passing rounds)

  // S1: stats1 over x (+ weight pre-transpose in block (0,0,0))
  conv_statsR<1, 4, 2000, 256, 2, 4><<<dim3(2, BSZ, NND), dim3(256), 0, stream>>>(
      x, 2000, (long)NND * 2000, 0, w1, p1, w2, w3, w2t, w3t);
  // conv1-apply (in-block scs1) + conv2 (pooled raw out) + stats2 partials
  fused1<<<dim3(1, BSZ, NND), dim3(256), 0, stream>>>(
      x, w1, p1, g1, b1, w2t, y2p, p2);
  // BN2-apply (in-block scs2) + conv3 (pooled raw out) + stats3 partials
  fused2<<<dim3(1, BSZ, NND), dim3(256), 0, stream>>>(
      y2p, p2, g2, b2, w3t, y3p, p3);
  // BN3 (in-block scs3) + ReLU + avg -> feat
  feat_apply<<<dim3(1, BSZ, NND), dim3(256), 0, stream>>>(
      y3p, p3, g3, b3, feat);
  // graph tail
  graph_head<<<dim3(BSZ), dim3(256), 0, stream>>>(
      feat, gw1, gb1, gw2, gb2, gw3, gb3, fw1, fb1, fw2, fb2, (float*)d_out);
}

// Round 14
// 218.296 us; speedup vs baseline: 1.2153x; 1.2153x over previous
//
#include <hip/hip_runtime.h>

#define BSZ 256
#define NND 22
#define BN_EPS 1e-5f

// ---------------------------------------------------------------------------
// conv core for CIN<=4 (used by S1 only). c-loop unroll-1 ON PURPOSE
// (R4-R7 lesson): full unroll at CIN>=4 blows VGPR to 164-256.
// ---------------------------------------------------------------------------
template<int CIN, int COUT, int R, int SROW>
__device__ __forceinline__ void conv_coreR(
    const float (*s_in)[SROW], const float* s_w, int tid, float y[COUT][R]) {
#pragma unroll
  for (int o = 0; o < COUT; o++)
#pragma unroll
    for (int r = 0; r < R; r++) y[o][r] = 0.f;
#pragma unroll 1
  for (int c = 0; c < CIN; c++) {
    float xr[R + 6];
    if constexpr (R == 4) {
      const float4* xp = (const float4*)&s_in[c][4 * tid];
      float4 xa = xp[0], xb = xp[1];
      float2 xc = *(const float2*)&s_in[c][4 * tid + 8];
      xr[0] = xa.x; xr[1] = xa.y; xr[2] = xa.z; xr[3] = xa.w;
      xr[4] = xb.x; xr[5] = xb.y; xr[6] = xb.z; xr[7] = xb.w;
      xr[8] = xc.x; xr[9] = xc.y;
    } else {
      const float2* xp = (const float2*)&s_in[c][2 * tid];
      float2 x0 = xp[0], x1 = xp[1], x2 = xp[2], x3 = xp[3];
      xr[0] = x0.x; xr[1] = x0.y; xr[2] = x1.x; xr[3] = x1.y;
      xr[4] = x2.x; xr[5] = x2.y; xr[6] = x3.x; xr[7] = x3.y;
    }
#pragma unroll
    for (int k = 0; k < 7; k++) {
      const float4* wp = (const float4*)&s_w[(c * 7 + k) * COUT];
#pragma unroll
      for (int o4 = 0; o4 < COUT / 4; o4++) {
        float4 wv = wp[o4];
#pragma unroll
        for (int r = 0; r < R; r++) {
          y[4 * o4 + 0][r] += wv.x * xr[r + k];
          y[4 * o4 + 1][r] += wv.y * xr[r + k];
          y[4 * o4 + 2][r] += wv.z * xr[r + k];
          y[4 * o4 + 3][r] += wv.w * xr[r + k];
        }
      }
    }
  }
}

template<int CIN, int COUT, int NTH>
__device__ __forceinline__ void stage_weights(const float* __restrict__ w,
                                              float* s_w, int tid) {
  for (int i = tid; i < CIN * 7 * COUT; i += NTH) {
    int c = i / (7 * COUT), k = (i / COUT) % 7, o = i % COUT;
    s_w[i] = w[(o * CIN + c) * 7 + k];
  }
}

// ---------------------------------------------------------------------------
// S1: stats of conv1 over x -> private partial slot. (proven)
// grid: (2, BSZ, NND), block 256.
// ---------------------------------------------------------------------------
template<int CIN, int COUT, int LIN, int NTH, int NT, int R>
__global__ __launch_bounds__(NTH) void conv_statsR(
    const float* __restrict__ in, long sn, long sb, long sc,
    const float* __restrict__ w, float* __restrict__ part) {
  const int TILE = R * NTH;
  const int SROW = TILE + 8;
  __shared__ alignas(16) float s_in[CIN][SROW];
  __shared__ alignas(16) float s_w[CIN * 7 * COUT];
  __shared__ float s_red[2][NTH / 64][COUT];
  int tid = threadIdx.x, n = blockIdx.z, b = blockIdx.y;
  int t0 = blockIdx.x * TILE;
  const float* base = in + (long)n * sn + (long)b * sb;
  stage_weights<CIN, COUT, NTH>(w, s_w, tid);
  for (int c = 0; c < CIN; c++)
    for (int i = tid; i < TILE + 6; i += NTH) {
      int l = t0 + i - 3;
      s_in[c][i] = (l >= 0 && l < LIN) ? base[(long)c * sc + l] : 0.f;
    }
  __syncthreads();
  float y[COUT][R];
  conv_coreR<CIN, COUT, R, SROW>(s_in, s_w, tid, y);
  bool valid = (t0 + R * tid) < LIN;
  int lane = tid & 63, wv = tid >> 6;
#pragma unroll
  for (int o = 0; o < COUT; o++) {
    float s = 0.f, q = 0.f;
    if (valid) {
#pragma unroll
      for (int r = 0; r < R; r++) { s += y[o][r]; q += y[o][r] * y[o][r]; }
    }
#pragma unroll
    for (int off = 32; off > 0; off >>= 1) {
      s += __shfl_down(s, off, 64);
      q += __shfl_down(q, off, 64);
    }
    if (lane == 0) { s_red[0][wv][o] = s; s_red[1][wv][o] = q; }
  }
  __syncthreads();
  if (tid < COUT) {
    float s = 0.f, q = 0.f;
#pragma unroll
    for (int g = 0; g < NTH / 64; g++) { s += s_red[0][g][tid]; q += s_red[1][g][tid]; }
    long slot = ((long)n * NT + blockIdx.x) * BSZ + b;
    part[slot * (2 * COUT) + tid] = s;
    part[slot * (2 * COUT) + COUT + tid] = q;
  }
}

// ---------------------------------------------------------------------------
// Reduce partials -> BN scale/shift. scs[n*64+o]=scale, scs[n*64+32+o]=shift
// Optionally (w2t != nullptr, block 0) also pre-transposes conv2/conv3
// weights to [c][k][o] global buffers (folded prep launch, R12-verified).
// ---------------------------------------------------------------------------
template<int C, int NSLOT, int LIN>
__global__ __launch_bounds__(256) void stats_reduce(
    const float* __restrict__ part,
    const float* __restrict__ gamma, const float* __restrict__ beta,
    float* __restrict__ scs,
    const float* __restrict__ w2, const float* __restrict__ w3,
    float* __restrict__ w2t, float* __restrict__ w3t) {
  const int V = 2 * C;
  const int GRP = 256 / V;
  int n = blockIdx.x, tid = threadIdx.x;
  int j = tid % V, g = tid / V;
  const float* p = part + (long)n * NSLOT * V;
  float s = 0.f;
  for (int sl = g; sl < NSLOT; sl += GRP) s += p[(long)sl * V + j];
  __shared__ float red[V][GRP];
  __shared__ float tot[V];
  red[j][g] = s;
  __syncthreads();
  if (tid < V) {
    float t = 0.f;
#pragma unroll
    for (int gg = 0; gg < GRP; gg++) t += red[tid][gg];
    tot[tid] = t;
  }
  __syncthreads();
  if (tid < C) {
    float cnt = (float)BSZ * (float)LIN;
    float m = tot[tid] / cnt;
    float var = tot[C + tid] / cnt - m * m;
    float istd = 1.0f / sqrtf(var + BN_EPS);
    float scl = gamma[tid] * istd;
    scs[n * 64 + tid] = scl;
    scs[n * 64 + 32 + tid] = beta[tid] - m * scl;
  }
  if (w2t != nullptr && blockIdx.x == 0) {
    if (tid < 224) {
      int c = tid / 56, k = (tid / 8) % 7, o = tid & 7;
      w2t[tid] = w2[(o * 4 + c) * 7 + k];
    }
    for (int i = tid; i < 896; i += 256) {
      int c = i / 112, k = (i / 16) % 7, o = i & 15;
      w3t[i] = w3[(o * 8 + c) * 7 + k];
    }
  }
}

// ---------------------------------------------------------------------------
// F1: conv1+BN1+ReLU+pool -> h1 (LDS ONLY) -> conv2 -> pooled raw conv2 to
// global (y2p; scale2>0 so maxpool∘relu∘BN == relu∘BN∘maxpool) + stats2
// partials. Weights via SGPR (uniform loads). grid: (1, B, N), block 256.
// ---------------------------------------------------------------------------
__global__ __launch_bounds__(256) void fused1(
    const float* __restrict__ x,      // (B, N, 2000)
    const float* __restrict__ w1,     // (4,1,7)
    const float* __restrict__ scs1,
    const float* __restrict__ w2t,    // [c][k][o] transposed conv2 weights
    float* __restrict__ y2p,          // [n][b][8][500] pooled raw conv2
    float* __restrict__ p2) {         // [(n*256+b)*16]
  __shared__ alignas(16) float s_x[2016];       // s_x[j+4] = x[j]
  __shared__ alignas(16) float s_h1[5][1008];   // row 4 = garbage prefetch row
  __shared__ float s_sc[4], s_sh[4];
  __shared__ float s_red[2][4][8];
  int tid = threadIdx.x, n = blockIdx.z, b = blockIdx.y;
  const float* xb = x + (long)b * (NND * 2000) + (long)n * 2000;
  if (tid < 4) { s_sc[tid] = scs1[n * 64 + tid]; s_sh[tid] = scs1[n * 64 + 32 + tid]; }
  {  // batched staging: both global loads issued before any LDS write
    float4 a0 = *(const float4*)&xb[4 * tid];
    float4 a1;
    bool m1 = tid + 256 < 500;
    if (m1) a1 = *(const float4*)&xb[4 * (tid + 256)];
    *(float4*)&s_x[4 * tid + 4] = a0;
    if (m1) *(float4*)&s_x[4 * (tid + 256) + 4] = a1;
  }
  if (tid == 0) {
    *(float4*)&s_x[0] = make_float4(0.f, 0.f, 0.f, 0.f);
    *(float4*)&s_x[2004] = make_float4(0.f, 0.f, 0.f, 0.f);
  }
  __syncthreads();
  // ---- Phase A: conv1 (8 pos/thread) + BN1 + ReLU + pool -> s_h1 ----
  if (tid < 250) {                                  // 8*250 = 2000 exactly
    float xr[16];
    const float4* xp = (const float4*)&s_x[8 * tid];
#pragma unroll
    for (int v = 0; v < 4; v++) {
      float4 t = xp[v];
      xr[4 * v + 0] = t.x; xr[4 * v + 1] = t.y;
      xr[4 * v + 2] = t.z; xr[4 * v + 3] = t.w;
    }
    float y[4][8];
#pragma unroll
    for (int o = 0; o < 4; o++)
#pragma unroll
      for (int r = 0; r < 8; r++) y[o][r] = 0.f;
#pragma unroll
    for (int k = 0; k < 7; k++) {
      float w0 = w1[0 * 7 + k], w1v = w1[1 * 7 + k];
      float w2v = w1[2 * 7 + k], w3v = w1[3 * 7 + k];
#pragma unroll
      for (int r = 0; r < 8; r++) {
        y[0][r] += w0 * xr[r + k + 1];
        y[1][r] += w1v * xr[r + k + 1];
        y[2][r] += w2v * xr[r + k + 1];
        y[3][r] += w3v * xr[r + k + 1];
      }
    }
#pragma unroll
    for (int o = 0; o < 4; o++) {
      float a0 = y[o][0] * s_sc[o] + s_sh[o], a1 = y[o][1] * s_sc[o] + s_sh[o];
      float a2 = y[o][2] * s_sc[o] + s_sh[o], a3 = y[o][3] * s_sc[o] + s_sh[o];
      float a4 = y[o][4] * s_sc[o] + s_sh[o], a5 = y[o][5] * s_sc[o] + s_sh[o];
      float a6 = y[o][6] * s_sc[o] + s_sh[o], a7 = y[o][7] * s_sc[o] + s_sh[o];
      float4 v;
      v.x = fmaxf(fmaxf(a0, a1), 0.f);
      v.y = fmaxf(fmaxf(a2, a3), 0.f);
      v.z = fmaxf(fmaxf(a4, a5), 0.f);
      v.w = fmaxf(fmaxf(a6, a7), 0.f);
      *(float4*)&s_h1[o][4 * tid + 4] = v;      // 16B-aligned, conflict-free
    }
  }
  if (tid < 4) {
    *(float4*)&s_h1[tid][0] = make_float4(0.f, 0.f, 0.f, 0.f);
    *(float4*)&s_h1[tid][1004] = make_float4(0.f, 0.f, 0.f, 0.f);
  }
  __syncthreads();
  // ---- Phase B: conv2 (pipelined x-reads) -> stats2 + pooled raw y2p ----
  float y2[8][4];
#pragma unroll
  for (int o = 0; o < 8; o++)
#pragma unroll
    for (int r = 0; r < 4; r++) y2[o][r] = 0.f;
  if (tid < 250) {                                  // 4*250 = 1000 exactly
    const float4* xp0 = (const float4*)&s_h1[0][4 * tid];
    float4 n0 = xp0[0], n1 = xp0[1], n2 = xp0[2];
#pragma unroll 1
    for (int c = 0; c < 4; c++) {
      float4 c0 = n0, c1 = n1, c2 = n2;
      const float4* xpn = (const float4*)&s_h1[c + 1][4 * tid];  // row4 garbage ok
      n0 = xpn[0]; n1 = xpn[1]; n2 = xpn[2];
      float xr[12];
      xr[0] = c0.x; xr[1] = c0.y; xr[2] = c0.z; xr[3] = c0.w;
      xr[4] = c1.x; xr[5] = c1.y; xr[6] = c1.z; xr[7] = c1.w;
      xr[8] = c2.x; xr[9] = c2.y; xr[10] = c2.z; xr[11] = c2.w;
#pragma unroll
      for (int k = 0; k < 7; k++) {
        float4 w0 = *(const float4*)&w2t[(c * 7 + k) * 8];       // s_load
        float4 w1v = *(const float4*)&w2t[(c * 7 + k) * 8 + 4];
#pragma unroll
        for (int r = 0; r < 4; r++) {
          float xv = xr[r + k + 1];
          y2[0][r] += w0.x * xv;
          y2[1][r] += w0.y * xv;
          y2[2][r] += w0.z * xv;
          y2[3][r] += w0.w * xv;
          y2[4][r] += w1v.x * xv;
          y2[5][r] += w1v.y * xv;
          y2[6][r] += w1v.z * xv;
          y2[7][r] += w1v.w * xv;
        }
      }
    }
    long yb = ((long)n * BSZ + b) * 4000 + 2 * tid;
#pragma unroll
    for (int o = 0; o < 8; o++) {
      float2 v;
      v.x = fmaxf(y2[o][0], y2[o][1]);
      v.y = fmaxf(y2[o][2], y2[o][3]);
      *(float2*)&y2p[yb + o * 500] = v;
    }
  }
  int lane = tid & 63, wv = tid >> 6;
#pragma unroll
  for (int o = 0; o < 8; o++) {
    float s = y2[o][0] + y2[o][1] + y2[o][2] + y2[o][3];
    float q = y2[o][0] * y2[o][0] + y2[o][1] * y2[o][1] +
              y2[o][2] * y2[o][2] + y2[o][3] * y2[o][3];
#pragma unroll
    for (int off = 32; off > 0; off >>= 1) {
      s += __shfl_down(s, off, 64);
      q += __shfl_down(q, off, 64);
    }
    if (lane == 0) { s_red[0][wv][o] = s; s_red[1][wv][o] = q; }
  }
  __syncthreads();
  if (tid < 8) {
    float s = 0.f, q = 0.f;
#pragma unroll
    for (int g = 0; g < 4; g++) { s += s_red[0][g][tid]; q += s_red[1][g][tid]; }
    long slot = (long)n * BSZ + b;
    p2[slot * 16 + tid] = s;
    p2[slot * 16 + 8 + tid] = q;
  }
}

// ---------------------------------------------------------------------------
// F2: read y2p, BN2+ReLU -> h2 in LDS, conv3 (channel-split, pipelined
// x-reads via garbage row s_h2[8]) -> pooled raw conv3 (y3p) + stats3
// partials. grid: (1, B, N), block 256.
// ---------------------------------------------------------------------------
__global__ __launch_bounds__(256) void fused2(
    const float* __restrict__ y2p,    // [n][b][8][500]
    const float* __restrict__ scs2,
    const float* __restrict__ w3t,    // [c][k][o] transposed conv3 weights
    float* __restrict__ y3p,          // [n][b][16][250] pooled raw conv3
    float* __restrict__ p3) {         // [(n*256+b)*32]
  __shared__ alignas(16) float s_h2[9][512];    // row 8 = garbage prefetch row
  __shared__ float s_sc[8], s_sh[8];
  __shared__ float s_red[2][4][8];
  int tid = threadIdx.x, n = blockIdx.z, b = blockIdx.y;
  if (tid < 8) { s_sc[tid] = scs2[n * 64 + tid]; s_sh[tid] = scs2[n * 64 + 32 + tid]; }
  __syncthreads();
  // batched staging: 4 global loads issued together, then BN2+ReLU -> s_h2
  const float* yb2 = y2p + ((long)n * BSZ + b) * 4000;
  {
    int i0 = tid, i1 = tid + 256, i2 = tid + 512, i3 = tid + 768;
    int c0 = i0 / 125, j0 = i0 % 125;
    int c1 = i1 / 125, j1 = i1 % 125;
    int c2 = i2 / 125, j2 = i2 % 125;
    int c3 = i3 / 125, j3 = i3 % 125;
    bool m3 = i3 < 1000;
    float4 a0 = *(const float4*)&yb2[c0 * 500 + 4 * j0];
    float4 a1 = *(const float4*)&yb2[c1 * 500 + 4 * j1];
    float4 a2 = *(const float4*)&yb2[c2 * 500 + 4 * j2];
    float4 a3;
    if (m3) a3 = *(const float4*)&yb2[c3 * 500 + 4 * j3];
    float sc, sh;
    sc = s_sc[c0]; sh = s_sh[c0];
    a0.x = fmaxf(a0.x * sc + sh, 0.f); a0.y = fmaxf(a0.y * sc + sh, 0.f);
    a0.z = fmaxf(a0.z * sc + sh, 0.f); a0.w = fmaxf(a0.w * sc + sh, 0.f);
    *(float4*)&s_h2[c0][4 * j0 + 4] = a0;
    sc = s_sc[c1]; sh = s_sh[c1];
    a1.x = fmaxf(a1.x * sc + sh, 0.f); a1.y = fmaxf(a1.y * sc + sh, 0.f);
    a1.z = fmaxf(a1.z * sc + sh, 0.f); a1.w = fmaxf(a1.w * sc + sh, 0.f);
    *(float4*)&s_h2[c1][4 * j1 + 4] = a1;
    sc = s_sc[c2]; sh = s_sh[c2];
    a2.x = fmaxf(a2.x * sc + sh, 0.f); a2.y = fmaxf(a2.y * sc + sh, 0.f);
    a2.z = fmaxf(a2.z * sc + sh, 0.f); a2.w = fmaxf(a2.w * sc + sh, 0.f);
    *(float4*)&s_h2[c2][4 * j2 + 4] = a2;
    if (m3) {
      sc = s_sc[c3]; sh = s_sh[c3];
      a3.x = fmaxf(a3.x * sc + sh, 0.f); a3.y = fmaxf(a3.y * sc + sh, 0.f);
      a3.z = fmaxf(a3.z * sc + sh, 0.f); a3.w = fmaxf(a3.w * sc + sh, 0.f);
      *(float4*)&s_h2[c3][4 * j3 + 4] = a3;
    }
  }
  if (tid < 8) {
    *(float4*)&s_h2[tid][0] = make_float4(0.f, 0.f, 0.f, 0.f);
    *(float4*)&s_h2[tid][504] = make_float4(0.f, 0.f, 0.f, 0.f);
  }
  __syncthreads();
  // conv3 channel-split over in-LDS h2; pipelined x-reads; SGPR weights
  int og = __builtin_amdgcn_readfirstlane(tid >> 7);  // wave-uniform
  int pt = tid & 127;
  bool valid = pt < 125;                            // 4*125 = 500 exactly
  float y3[8][4];
#pragma unroll
  for (int o = 0; o < 8; o++)
#pragma unroll
    for (int r = 0; r < 4; r++) y3[o][r] = 0.f;
  if (valid) {
    const float4* xp0 = (const float4*)&s_h2[0][4 * pt];
    float4 n0 = xp0[0], n1 = xp0[1], n2 = xp0[2];
#pragma unroll 1
    for (int c = 0; c < 8; c++) {
      float4 d0 = n0, d1 = n1, d2 = n2;
      const float4* xpn = (const float4*)&s_h2[c + 1][4 * pt];  // row8 garbage ok
      n0 = xpn[0]; n1 = xpn[1]; n2 = xpn[2];
      float xr[12];
      xr[0] = d0.x; xr[1] = d0.y; xr[2] = d0.z; xr[3] = d0.w;
      xr[4] = d1.x; xr[5] = d1.y; xr[6] = d1.z; xr[7] = d1.w;
      xr[8] = d2.x; xr[9] = d2.y; xr[10] = d2.z; xr[11] = d2.w;
#pragma unroll
      for (int k = 0; k < 7; k++) {
        float4 w0 = *(const float4*)&w3t[(c * 7 + k) * 16 + og * 8];
        float4 w1v = *(const float4*)&w3t[(c * 7 + k) * 16 + og * 8 + 4];
#pragma unroll
        for (int r = 0; r < 4; r++) {
          float xv = xr[r + k + 1];
          y3[0][r] += w0.x * xv;
          y3[1][r] += w0.y * xv;
          y3[2][r] += w0.z * xv;
          y3[3][r] += w0.w * xv;
          y3[4][r] += w1v.x * xv;
          y3[5][r] += w1v.y * xv;
          y3[6][r] += w1v.z * xv;
          y3[7][r] += w1v.w * xv;
        }
      }
    }
    long yb = (((long)n * BSZ + b) * 16 + og * 8) * 250 + 2 * pt;
#pragma unroll
    for (int o = 0; o < 8; o++) {
      float2 v;
      v.x = fmaxf(y3[o][0], y3[o][1]);
      v.y = fmaxf(y3[o][2], y3[o][3]);
      *(float2*)&y3p[yb + o * 250] = v;
    }
  }
  int lane = tid & 63, wv = tid >> 6;
#pragma unroll
  for (int o = 0; o < 8; o++) {
    float s = y3[o][0] + y3[o][1] + y3[o][2] + y3[o][3];
    float q = y3[o][0] * y3[o][0] + y3[o][1] * y3[o][1] +
              y3[o][2] * y3[o][2] + y3[o][3] * y3[o][3];
#pragma unroll
    for (int off = 32; off > 0; off >>= 1) {
      s += __shfl_down(s, off, 64);
      q += __shfl_down(q, off, 64);
    }
    if (lane == 0) { s_red[0][wv][o] = s; s_red[1][wv][o] = q; }
  }
  __syncthreads();
  if (tid < 16) {
    int og2 = tid >> 3, o = tid & 7;
    float s = s_red[0][2 * og2][o] + s_red[0][2 * og2 + 1][o];
    float q = s_red[1][2 * og2][o] + s_red[1][2 * og2 + 1][o];
    long slot = (long)n * BSZ + b;
    p3[slot * 32 + tid] = s;
    p3[slot * 32 + 16 + tid] = q;
  }
}

// ---------------------------------------------------------------------------
// F3: BN3 + ReLU + avg over pooled raw conv3 -> feat[b][n][16].
// grid: (1, B, N), block 256 (16 chans x 16 threads). SEPARATE kernel:
// R12 lesson — folding into 256-block graph_head collapses parallelism.
// ---------------------------------------------------------------------------
__global__ __launch_bounds__(256) void feat_apply(
    const float* __restrict__ y3p,
    const float* __restrict__ scs3,
    float* __restrict__ feat) {
  int tid = threadIdx.x, n = blockIdx.z, b = blockIdx.y;
  int ch = tid >> 4, s = tid & 15;
  const float* yb = y3p + (((long)n * BSZ + b) * 16 + ch) * 250;
  float sc = scs3[n * 64 + ch], sh = scs3[n * 64 + 32 + ch];
  float acc = 0.f;
  for (int j = s; j < 125; j += 16) {
    float2 v = *(const float2*)&yb[2 * j];
    acc += fmaxf(v.x * sc + sh, 0.f) + fmaxf(v.y * sc + sh, 0.f);
  }
#pragma unroll
  for (int off = 8; off > 0; off >>= 1) acc += __shfl_down(acc, off, 16);
  if (s == 0) feat[((long)b * NND + n) * 16 + ch] = acc * (1.0f / 250.f);
}

// ---------------------------------------------------------------------------
// Graph tail: adjacency (top-4 incl self) + 3 GCN layers + node-mean + MLP
// grid: (B), block: 256.
// ---------------------------------------------------------------------------
__global__ __launch_bounds__(256) void graph_head(
    const float* __restrict__ feat,
    const float* __restrict__ gw1, const float* __restrict__ gb1,
    const float* __restrict__ gw2, const float* __restrict__ gb2,
    const float* __restrict__ gw3, const float* __restrict__ gb3,
    const float* __restrict__ fw1, const float* __restrict__ fb1,
    const float* __restrict__ fw2, const float* __restrict__ fb2,
    float* __restrict__ out) {
  int b = blockIdx.x, tid = threadIdx.x;
  __shared__ float s_feat[NND][16];
  __shared__ float s_sq[NND];
  __shared__ float s_dist[NND][NND];
  __shared__ float s_adj[NND][NND];
  __shared__ float s_x[NND][128];
  __shared__ float s_t[NND][128];
  __shared__ float s_pool[128];
  __shared__ float s_h[64];
  for (int i = tid; i < NND * 16; i += 256) s_feat[i >> 4][i & 15] = feat[b * NND * 16 + i];
  __syncthreads();
  if (tid < NND) {
    float s = 0.f;
    for (int c = 0; c < 16; c++) s += s_feat[tid][c] * s_feat[tid][c];
    s_sq[tid] = s;
  }
  __syncthreads();
  for (int i = tid; i < NND * NND; i += 256) {
    int nn = i / NND, m = i % NND;
    float d = 0.f;
    for (int c = 0; c < 16; c++) d += s_feat[nn][c] * s_feat[m][c];
    s_dist[nn][m] = s_sq[nn] + s_sq[m] - 2.f * d;  // diagonal exactly 0
    s_adj[nn][m] = 0.f;
  }
  __syncthreads();
  if (tid < NND) {  // top-4 smallest, ties -> earliest index (matches top_k)
    unsigned used = 0;
    for (int j = 0; j < 4; j++) {
      float best = 3.4e38f; int bi = 0;
      for (int m = 0; m < NND; m++)
        if (!((used >> m) & 1u) && s_dist[tid][m] < best) { best = s_dist[tid][m]; bi = m; }
      used |= 1u << bi;
      s_adj[tid][bi] = 0.25f;
    }
  }
  __syncthreads();
  for (int i = tid; i < NND * 32; i += 256) {
    int nn = i / 32, f = i % 32;
    float a = 0.f;
    for (int c = 0; c < 16; c++) a += s_feat[nn][c] * gw1[c * 32 + f];
    s_t[nn][f] = a;
  }
  __syncthreads();
  for (int i = tid; i < NND * 32; i += 256) {
    int nn = i / 32, f = i % 32;
    float a = gb1[f];
    for (int m = 0; m < NND; m++) a += s_adj[nn][m] * s_t[m][f];
    s_x[nn][f] = fmaxf(a, 0.f);
  }
  __syncthreads();
  for (int i = tid; i < NND * 64; i += 256) {
    int nn = i / 64, f = i % 64;
    float a = 0.f;
    for (int c = 0; c < 32; c++) a += s_x[nn][c] * gw2[c * 64 + f];
    s_t[nn][f] = a;
  }
  __syncthreads();
  for (int i = tid; i < NND * 64; i += 256) {
    int nn = i / 64, f = i % 64;
    float a = gb2[f];
    for (int m = 0; m < NND; m++) a += s_adj[nn][m] * s_t[m][f];
    s_x[nn][f] = fmaxf(a, 0.f);
  }
  __syncthreads();
  for (int i = tid; i < NND * 128; i += 256) {
    int nn = i / 128, f = i % 128;
    float a = 0.f;
    for (int c = 0; c < 64; c++) a += s_x[nn][c] * gw3[c * 128 + f];
    s_t[nn][f] = a;
  }
  __syncthreads();
  for (int i = tid; i < NND * 128; i += 256) {
    int nn = i / 128, f = i % 128;
    float a = gb3[f];
    for (int m = 0; m < NND; m++) a += s_adj[nn][m] * s_t[m][f];
    s_x[nn][f] = fmaxf(a, 0.f);
  }
  __syncthreads();
  if (tid < 128) {
    float a = 0.f;
    for (int m = 0; m < NND; m++) a += s_x[m][tid];
    s_pool[tid] = a * (1.0f / (float)NND);
  }
  __syncthreads();
  if (tid < 64) {
    float a = fb1[tid];
    for (int c = 0; c < 128; c++) a += s_pool[c] * fw1[c * 64 + tid];
    s_h[tid] = a;
  }
  __syncthreads();
  if (tid < 4) {
    float a = fb2[tid];
    for (int c = 0; c < 64; c++) a += s_h[c] * fw2[c * 4 + tid];
    out[b * 4 + tid] = a;
  }
}

extern "C" void kernel_launch(void* const* d_in, const int* in_sizes, int n_in,
                              void* d_out, int out_size, void* d_ws, size_t ws_size,
                              hipStream_t stream) {
  (void)in_sizes; (void)n_in; (void)out_size; (void)ws_size;
  const float* x   = (const float*)d_in[0];
  const float* w1  = (const float*)d_in[1];
  const float* g1  = (const float*)d_in[2];
  const float* b1  = (const float*)d_in[3];
  const float* w2  = (const float*)d_in[4];
  const float* g2  = (const float*)d_in[5];
  const float* b2  = (const float*)d_in[6];
  const float* w3  = (const float*)d_in[7];
  const float* g3  = (const float*)d_in[8];
  const float* b3  = (const float*)d_in[9];
  const float* gw1 = (const float*)d_in[10];
  const float* gb1 = (const float*)d_in[11];
  const float* gw2 = (const float*)d_in[12];
  const float* gb2 = (const float*)d_in[13];
  const float* gw3 = (const float*)d_in[14];
  const float* gb3 = (const float*)d_in[15];
  const float* fw1 = (const float*)d_in[16];
  const float* fb1 = (const float*)d_in[17];
  const float* fw2 = (const float*)d_in[18];
  const float* fb2 = (const float*)d_in[19];

  float* ws = (float*)d_ws;
  const long Y2 = (long)NND * BSZ * 8 * 500;    // 22,528,000 floats
  const long Y3 = (long)NND * BSZ * 16 * 250;   // 22,528,000 floats
  float* y2p  = ws;
  float* y3p  = y2p + Y2;
  float* feat = y3p + Y3;                       // B*N*16 = 90,112
  float* scs1 = feat + (long)BSZ * NND * 16;
  float* scs2 = scs1 + NND * 64;
  float* scs3 = scs2 + NND * 64;
  float* p1   = scs3 + NND * 64;                // 22*512 slots * 8
  float* p2   = p1 + (long)NND * 512 * 8;       // 22*256 slots * 16
  float* p3   = p2 + (long)NND * 256 * 16;      // 22*256 slots * 32
  float* w2t  = p3 + (long)NND * 256 * 32;      // 224
  float* w3t  = w2t + 224;                      // 896
  // total ws ~= 181 MB (same budget as prior passing rounds)

  // S1: stats1 over x
  conv_statsR<1, 4, 2000, 256, 2, 4><<<dim3(2, BSZ, NND), dim3(256), 0, stream>>>(
      x, 2000, (long)NND * 2000, 0, w1, p1);
  // reduce1 (+ weight pre-transpose in block 0)
  stats_reduce<4, 512, 2000><<<dim3(NND), dim3(256), 0, stream>>>(
      p1, g1, b1, scs1, w2, w3, w2t, w3t);
  // conv1-apply + conv2 (pooled raw out) + stats2 (fused; h1 stays in LDS)
  fused1<<<dim3(1, BSZ, NND), dim3(256), 0, stream>>>(x, w1, scs1, w2t, y2p, p2);
  stats_reduce<8, 256, 1000><<<dim3(NND), dim3(256), 0, stream>>>(
      p2, g2, b2, scs2, nullptr, nullptr, nullptr, nullptr);
  // BN2-apply + conv3 (pooled raw out) + stats3 (fused; no conv2 recompute)
  fused2<<<dim3(1, BSZ, NND), dim3(256), 0, stream>>>(y2p, scs2, w3t, y3p, p3);
  stats_reduce<16, 256, 500><<<dim3(NND), dim3(256), 0, stream>>>(
      p3, g3, b3, scs3, nullptr, nullptr, nullptr, nullptr);
  // BN3 + ReLU + avg -> feat (separate 5632-block kernel; R12 lesson)
  feat_apply<<<dim3(1, BSZ, NND), dim3(256), 0, stream>>>(y3p, scs3, feat);
  // graph tail
  graph_head<<<dim3(BSZ), dim3(256), 0, stream>>>(
      feat, gw1, gb1, gw2, gb2, gw3, gb3, fw1, fb1, fw2, fb2, (float*)d_out);
}

// Round 15
// 213.870 us; speedup vs baseline: 1.2404x; 1.0207x over previous
//
#include <hip/hip_runtime.h>

#define BSZ 256
#define NND 22
#define BN_EPS 1e-5f

typedef float v2f __attribute__((ext_vector_type(2)));

// ---------------------------------------------------------------------------
// conv core for CIN<=4 (used by S1 only). c-loop unroll-1 ON PURPOSE
// (R4-R7 lesson): full unroll at CIN>=4 blows VGPR to 164-256.
// ---------------------------------------------------------------------------
template<int CIN, int COUT, int R, int SROW>
__device__ __forceinline__ void conv_coreR(
    const float (*s_in)[SROW], const float* s_w, int tid, float y[COUT][R]) {
#pragma unroll
  for (int o = 0; o < COUT; o++)
#pragma unroll
    for (int r = 0; r < R; r++) y[o][r] = 0.f;
#pragma unroll 1
  for (int c = 0; c < CIN; c++) {
    float xr[R + 6];
    if constexpr (R == 4) {
      const float4* xp = (const float4*)&s_in[c][4 * tid];
      float4 xa = xp[0], xb = xp[1];
      float2 xc = *(const float2*)&s_in[c][4 * tid + 8];
      xr[0] = xa.x; xr[1] = xa.y; xr[2] = xa.z; xr[3] = xa.w;
      xr[4] = xb.x; xr[5] = xb.y; xr[6] = xb.z; xr[7] = xb.w;
      xr[8] = xc.x; xr[9] = xc.y;
    } else {
      const float2* xp = (const float2*)&s_in[c][2 * tid];
      float2 x0 = xp[0], x1 = xp[1], x2 = xp[2], x3 = xp[3];
      xr[0] = x0.x; xr[1] = x0.y; xr[2] = x1.x; xr[3] = x1.y;
      xr[4] = x2.x; xr[5] = x2.y; xr[6] = x3.x; xr[7] = x3.y;
    }
#pragma unroll
    for (int k = 0; k < 7; k++) {
      const float4* wp = (const float4*)&s_w[(c * 7 + k) * COUT];
#pragma unroll
      for (int o4 = 0; o4 < COUT / 4; o4++) {
        float4 wv = wp[o4];
#pragma unroll
        for (int r = 0; r < R; r++) {
          y[4 * o4 + 0][r] += wv.x * xr[r + k];
          y[4 * o4 + 1][r] += wv.y * xr[r + k];
          y[4 * o4 + 2][r] += wv.z * xr[r + k];
          y[4 * o4 + 3][r] += wv.w * xr[r + k];
        }
      }
    }
  }
}

template<int CIN, int COUT, int NTH>
__device__ __forceinline__ void stage_weights(const float* __restrict__ w,
                                              float* s_w, int tid) {
  for (int i = tid; i < CIN * 7 * COUT; i += NTH) {
    int c = i / (7 * COUT), k = (i / COUT) % 7, o = i % COUT;
    s_w[i] = w[(o * CIN + c) * 7 + k];
  }
}

// ---------------------------------------------------------------------------
// S1: stats of conv1 over x -> private partial slot. (proven)
// grid: (2, BSZ, NND), block 256.
// ---------------------------------------------------------------------------
template<int CIN, int COUT, int LIN, int NTH, int NT, int R>
__global__ __launch_bounds__(NTH) void conv_statsR(
    const float* __restrict__ in, long sn, long sb, long sc,
    const float* __restrict__ w, float* __restrict__ part) {
  const int TILE = R * NTH;
  const int SROW = TILE + 8;
  __shared__ alignas(16) float s_in[CIN][SROW];
  __shared__ alignas(16) float s_w[CIN * 7 * COUT];
  __shared__ float s_red[2][NTH / 64][COUT];
  int tid = threadIdx.x, n = blockIdx.z, b = blockIdx.y;
  int t0 = blockIdx.x * TILE;
  const float* base = in + (long)n * sn + (long)b * sb;
  stage_weights<CIN, COUT, NTH>(w, s_w, tid);
  for (int c = 0; c < CIN; c++)
    for (int i = tid; i < TILE + 6; i += NTH) {
      int l = t0 + i - 3;
      s_in[c][i] = (l >= 0 && l < LIN) ? base[(long)c * sc + l] : 0.f;
    }
  __syncthreads();
  float y[COUT][R];
  conv_coreR<CIN, COUT, R, SROW>(s_in, s_w, tid, y);
  bool valid = (t0 + R * tid) < LIN;
  int lane = tid & 63, wv = tid >> 6;
#pragma unroll
  for (int o = 0; o < COUT; o++) {
    float s = 0.f, q = 0.f;
    if (valid) {
#pragma unroll
      for (int r = 0; r < R; r++) { s += y[o][r]; q += y[o][r] * y[o][r]; }
    }
#pragma unroll
    for (int off = 32; off > 0; off >>= 1) {
      s += __shfl_down(s, off, 64);
      q += __shfl_down(q, off, 64);
    }
    if (lane == 0) { s_red[0][wv][o] = s; s_red[1][wv][o] = q; }
  }
  __syncthreads();
  if (tid < COUT) {
    float s = 0.f, q = 0.f;
#pragma unroll
    for (int g = 0; g < NTH / 64; g++) { s += s_red[0][g][tid]; q += s_red[1][g][tid]; }
    long slot = ((long)n * NT + blockIdx.x) * BSZ + b;
    part[slot * (2 * COUT) + tid] = s;
    part[slot * (2 * COUT) + COUT + tid] = q;
  }
}

// ---------------------------------------------------------------------------
// Reduce partials -> BN scale/shift. scs[n*64+o]=scale, scs[n*64+32+o]=shift
// Optionally (w2t != nullptr, block 0) also pre-transposes conv2/conv3
// weights to [c][k][o] global buffers (folded prep launch, R12-verified).
// ---------------------------------------------------------------------------
template<int C, int NSLOT, int LIN>
__global__ __launch_bounds__(256) void stats_reduce(
    const float* __restrict__ part,
    const float* __restrict__ gamma, const float* __restrict__ beta,
    float* __restrict__ scs,
    const float* __restrict__ w2, const float* __restrict__ w3,
    float* __restrict__ w2t, float* __restrict__ w3t) {
  const int V = 2 * C;
  const int GRP = 256 / V;
  int n = blockIdx.x, tid = threadIdx.x;
  int j = tid % V, g = tid / V;
  const float* p = part + (long)n * NSLOT * V;
  float s = 0.f;
  for (int sl = g; sl < NSLOT; sl += GRP) s += p[(long)sl * V + j];
  __shared__ float red[V][GRP];
  __shared__ float tot[V];
  red[j][g] = s;
  __syncthreads();
  if (tid < V) {
    float t = 0.f;
#pragma unroll
    for (int gg = 0; gg < GRP; gg++) t += red[tid][gg];
    tot[tid] = t;
  }
  __syncthreads();
  if (tid < C) {
    float cnt = (float)BSZ * (float)LIN;
    float m = tot[tid] / cnt;
    float var = tot[C + tid] / cnt - m * m;
    float istd = 1.0f / sqrtf(var + BN_EPS);
    float scl = gamma[tid] * istd;
    scs[n * 64 + tid] = scl;
    scs[n * 64 + 32 + tid] = beta[tid] - m * scl;
  }
  if (w2t != nullptr && blockIdx.x == 0) {
    if (tid < 224) {
      int c = tid / 56, k = (tid / 8) % 7, o = tid & 7;
      w2t[tid] = w2[(o * 4 + c) * 7 + k];
    }
    for (int i = tid; i < 896; i += 256) {
      int c = i / 112, k = (i / 16) % 7, o = i & 15;
      w3t[i] = w3[(o * 8 + c) * 7 + k];
    }
  }
}

// ---------------------------------------------------------------------------
// F1: conv1+BN1+ReLU+pool -> h1 (LDS ONLY) -> conv2 -> pooled raw conv2 to
// global (y2p; scale2>0 so maxpool∘relu∘BN == relu∘BN∘maxpool) + stats2
// partials. Inner loops packed over CHANNEL PAIRS (v2f -> v_pk_fma_f32,
// 2x fp32 rate; weight pairs from consecutive SGPRs, x splat free).
// grid: (1, B, N), block 256.
// ---------------------------------------------------------------------------
__global__ __launch_bounds__(256) void fused1(
    const float* __restrict__ x,      // (B, N, 2000)
    const float* __restrict__ w1,     // (4,1,7)
    const float* __restrict__ scs1,
    const float* __restrict__ w2t,    // [c][k][o] transposed conv2 weights
    float* __restrict__ y2p,          // [n][b][8][500] pooled raw conv2
    float* __restrict__ p2) {         // [(n*256+b)*16]
  __shared__ alignas(16) float s_x[2016];       // s_x[j+4] = x[j]
  __shared__ alignas(16) float s_h1[5][1008];   // row 4 = garbage prefetch row
  __shared__ float s_sc[4], s_sh[4];
  __shared__ float s_red[2][4][8];
  int tid = threadIdx.x, n = blockIdx.z, b = blockIdx.y;
  const float* xb = x + (long)b * (NND * 2000) + (long)n * 2000;
  if (tid < 4) { s_sc[tid] = scs1[n * 64 + tid]; s_sh[tid] = scs1[n * 64 + 32 + tid]; }
  {  // batched staging: both global loads issued before any LDS write
    float4 a0 = *(const float4*)&xb[4 * tid];
    float4 a1;
    bool m1 = tid + 256 < 500;
    if (m1) a1 = *(const float4*)&xb[4 * (tid + 256)];
    *(float4*)&s_x[4 * tid + 4] = a0;
    if (m1) *(float4*)&s_x[4 * (tid + 256) + 4] = a1;
  }
  if (tid == 0) {
    *(float4*)&s_x[0] = make_float4(0.f, 0.f, 0.f, 0.f);
    *(float4*)&s_x[2004] = make_float4(0.f, 0.f, 0.f, 0.f);
  }
  __syncthreads();
  // ---- Phase A: conv1 (8 pos/thread, 2 channel-pairs) + BN1+ReLU+pool ----
  if (tid < 250) {                                  // 8*250 = 2000 exactly
    float xr[16];
    const float4* xp = (const float4*)&s_x[8 * tid];
#pragma unroll
    for (int v = 0; v < 4; v++) {
      float4 t = xp[v];
      xr[4 * v + 0] = t.x; xr[4 * v + 1] = t.y;
      xr[4 * v + 2] = t.z; xr[4 * v + 3] = t.w;
    }
    v2f yv[2][8];
#pragma unroll
    for (int oo = 0; oo < 2; oo++)
#pragma unroll
      for (int r = 0; r < 8; r++) { yv[oo][r].x = 0.f; yv[oo][r].y = 0.f; }
#pragma unroll
    for (int k = 0; k < 7; k++) {
      v2f wpA, wpB;
      wpA.x = w1[0 * 7 + k]; wpA.y = w1[1 * 7 + k];
      wpB.x = w1[2 * 7 + k]; wpB.y = w1[3 * 7 + k];
#pragma unroll
      for (int r = 0; r < 8; r++) {
        v2f xs; xs.x = xr[r + k + 1]; xs.y = xr[r + k + 1];
        yv[0][r] += wpA * xs;
        yv[1][r] += wpB * xs;
      }
    }
#pragma unroll
    for (int oo = 0; oo < 2; oo++) {
      // channel 2*oo (.x)
      {
        int o = 2 * oo;
        float a0 = yv[oo][0].x * s_sc[o] + s_sh[o], a1 = yv[oo][1].x * s_sc[o] + s_sh[o];
        float a2 = yv[oo][2].x * s_sc[o] + s_sh[o], a3 = yv[oo][3].x * s_sc[o] + s_sh[o];
        float a4 = yv[oo][4].x * s_sc[o] + s_sh[o], a5 = yv[oo][5].x * s_sc[o] + s_sh[o];
        float a6 = yv[oo][6].x * s_sc[o] + s_sh[o], a7 = yv[oo][7].x * s_sc[o] + s_sh[o];
        float4 v;
        v.x = fmaxf(fmaxf(a0, a1), 0.f);
        v.y = fmaxf(fmaxf(a2, a3), 0.f);
        v.z = fmaxf(fmaxf(a4, a5), 0.f);
        v.w = fmaxf(fmaxf(a6, a7), 0.f);
        *(float4*)&s_h1[o][4 * tid + 4] = v;
      }
      // channel 2*oo+1 (.y)
      {
        int o = 2 * oo + 1;
        float a0 = yv[oo][0].y * s_sc[o] + s_sh[o], a1 = yv[oo][1].y * s_sc[o] + s_sh[o];
        float a2 = yv[oo][2].y * s_sc[o] + s_sh[o], a3 = yv[oo][3].y * s_sc[o] + s_sh[o];
        float a4 = yv[oo][4].y * s_sc[o] + s_sh[o], a5 = yv[oo][5].y * s_sc[o] + s_sh[o];
        float a6 = yv[oo][6].y * s_sc[o] + s_sh[o], a7 = yv[oo][7].y * s_sc[o] + s_sh[o];
        float4 v;
        v.x = fmaxf(fmaxf(a0, a1), 0.f);
        v.y = fmaxf(fmaxf(a2, a3), 0.f);
        v.z = fmaxf(fmaxf(a4, a5), 0.f);
        v.w = fmaxf(fmaxf(a6, a7), 0.f);
        *(float4*)&s_h1[o][4 * tid + 4] = v;
      }
    }
  }
  if (tid < 4) {
    *(float4*)&s_h1[tid][0] = make_float4(0.f, 0.f, 0.f, 0.f);
    *(float4*)&s_h1[tid][1004] = make_float4(0.f, 0.f, 0.f, 0.f);
  }
  __syncthreads();
  // ---- Phase B: conv2 (pipelined x-reads, 4 channel-pairs) ----
  v2f y2v[4][4];
#pragma unroll
  for (int oo = 0; oo < 4; oo++)
#pragma unroll
    for (int r = 0; r < 4; r++) { y2v[oo][r].x = 0.f; y2v[oo][r].y = 0.f; }
  if (tid < 250) {                                  // 4*250 = 1000 exactly
    const float4* xp0 = (const float4*)&s_h1[0][4 * tid];
    float4 n0 = xp0[0], n1 = xp0[1], n2 = xp0[2];
#pragma unroll 1
    for (int c = 0; c < 4; c++) {
      float4 c0 = n0, c1 = n1, c2 = n2;
      const float4* xpn = (const float4*)&s_h1[c + 1][4 * tid];  // row4 garbage ok
      n0 = xpn[0]; n1 = xpn[1]; n2 = xpn[2];
      float xr[12];
      xr[0] = c0.x; xr[1] = c0.y; xr[2] = c0.z; xr[3] = c0.w;
      xr[4] = c1.x; xr[5] = c1.y; xr[6] = c1.z; xr[7] = c1.w;
      xr[8] = c2.x; xr[9] = c2.y; xr[10] = c2.z; xr[11] = c2.w;
#pragma unroll
      for (int k = 0; k < 7; k++) {
        float4 w0 = *(const float4*)&w2t[(c * 7 + k) * 8];       // s_load
        float4 w1v = *(const float4*)&w2t[(c * 7 + k) * 8 + 4];
        v2f wp0, wp1, wp2, wp3;
        wp0.x = w0.x; wp0.y = w0.y;
        wp1.x = w0.z; wp1.y = w0.w;
        wp2.x = w1v.x; wp2.y = w1v.y;
        wp3.x = w1v.z; wp3.y = w1v.w;
#pragma unroll
        for (int r = 0; r < 4; r++) {
          v2f xs; xs.x = xr[r + k + 1]; xs.y = xr[r + k + 1];
          y2v[0][r] += wp0 * xs;
          y2v[1][r] += wp1 * xs;
          y2v[2][r] += wp2 * xs;
          y2v[3][r] += wp3 * xs;
        }
      }
    }
    long yb = ((long)n * BSZ + b) * 4000 + 2 * tid;
#pragma unroll
    for (int oo = 0; oo < 4; oo++) {
      float2 vx, vy;
      vx.x = fmaxf(y2v[oo][0].x, y2v[oo][1].x);
      vx.y = fmaxf(y2v[oo][2].x, y2v[oo][3].x);
      *(float2*)&y2p[yb + (2 * oo) * 500] = vx;
      vy.x = fmaxf(y2v[oo][0].y, y2v[oo][1].y);
      vy.y = fmaxf(y2v[oo][2].y, y2v[oo][3].y);
      *(float2*)&y2p[yb + (2 * oo + 1) * 500] = vy;
    }
  }
  int lane = tid & 63, wv = tid >> 6;
#pragma unroll
  for (int o = 0; o < 8; o++) {
    float g0 = (o & 1) ? y2v[o >> 1][0].y : y2v[o >> 1][0].x;
    float g1 = (o & 1) ? y2v[o >> 1][1].y : y2v[o >> 1][1].x;
    float g2 = (o & 1) ? y2v[o >> 1][2].y : y2v[o >> 1][2].x;
    float g3 = (o & 1) ? y2v[o >> 1][3].y : y2v[o >> 1][3].x;
    float s = g0 + g1 + g2 + g3;
    float q = g0 * g0 + g1 * g1 + g2 * g2 + g3 * g3;
#pragma unroll
    for (int off = 32; off > 0; off >>= 1) {
      s += __shfl_down(s, off, 64);
      q += __shfl_down(q, off, 64);
    }
    if (lane == 0) { s_red[0][wv][o] = s; s_red[1][wv][o] = q; }
  }
  __syncthreads();
  if (tid < 8) {
    float s = 0.f, q = 0.f;
#pragma unroll
    for (int g = 0; g < 4; g++) { s += s_red[0][g][tid]; q += s_red[1][g][tid]; }
    long slot = (long)n * BSZ + b;
    p2[slot * 16 + tid] = s;
    p2[slot * 16 + 8 + tid] = q;
  }
}

// ---------------------------------------------------------------------------
// F2: read y2p, BN2+ReLU -> h2 in LDS, conv3 (channel-split, pipelined
// x-reads, 4 channel-pairs packed v_pk_fma) -> pooled raw conv3 (y3p) +
// stats3 partials. grid: (1, B, N), block 256.
// ---------------------------------------------------------------------------
__global__ __launch_bounds__(256) void fused2(
    const float* __restrict__ y2p,    // [n][b][8][500]
    const float* __restrict__ scs2,
    const float* __restrict__ w3t,    // [c][k][o] transposed conv3 weights
    float* __restrict__ y3p,          // [n][b][16][250] pooled raw conv3
    float* __restrict__ p3) {         // [(n*256+b)*32]
  __shared__ alignas(16) float s_h2[9][512];    // row 8 = garbage prefetch row
  __shared__ float s_sc[8], s_sh[8];
  __shared__ float s_red[2][4][8];
  int tid = threadIdx.x, n = blockIdx.z, b = blockIdx.y;
  if (tid < 8) { s_sc[tid] = scs2[n * 64 + tid]; s_sh[tid] = scs2[n * 64 + 32 + tid]; }
  __syncthreads();
  // batched staging: 4 global loads issued together, then BN2+ReLU -> s_h2
  const float* yb2 = y2p + ((long)n * BSZ + b) * 4000;
  {
    int i0 = tid, i1 = tid + 256, i2 = tid + 512, i3 = tid + 768;
    int c0 = i0 / 125, j0 = i0 % 125;
    int c1 = i1 / 125, j1 = i1 % 125;
    int c2 = i2 / 125, j2 = i2 % 125;
    int c3 = i3 / 125, j3 = i3 % 125;
    bool m3 = i3 < 1000;
    float4 a0 = *(const float4*)&yb2[c0 * 500 + 4 * j0];
    float4 a1 = *(const float4*)&yb2[c1 * 500 + 4 * j1];
    float4 a2 = *(const float4*)&yb2[c2 * 500 + 4 * j2];
    float4 a3;
    if (m3) a3 = *(const float4*)&yb2[c3 * 500 + 4 * j3];
    float sc, sh;
    sc = s_sc[c0]; sh = s_sh[c0];
    a0.x = fmaxf(a0.x * sc + sh, 0.f); a0.y = fmaxf(a0.y * sc + sh, 0.f);
    a0.z = fmaxf(a0.z * sc + sh, 0.f); a0.w = fmaxf(a0.w * sc + sh, 0.f);
    *(float4*)&s_h2[c0][4 * j0 + 4] = a0;
    sc = s_sc[c1]; sh = s_sh[c1];
    a1.x = fmaxf(a1.x * sc + sh, 0.f); a1.y = fmaxf(a1.y * sc + sh, 0.f);
    a1.z = fmaxf(a1.z * sc + sh, 0.f); a1.w = fmaxf(a1.w * sc + sh, 0.f);
    *(float4*)&s_h2[c1][4 * j1 + 4] = a1;
    sc = s_sc[c2]; sh = s_sh[c2];
    a2.x = fmaxf(a2.x * sc + sh, 0.f); a2.y = fmaxf(a2.y * sc + sh, 0.f);
    a2.z = fmaxf(a2.z * sc + sh, 0.f); a2.w = fmaxf(a2.w * sc + sh, 0.f);
    *(float4*)&s_h2[c2][4 * j2 + 4] = a2;
    if (m3) {
      sc = s_sc[c3]; sh = s_sh[c3];
      a3.x = fmaxf(a3.x * sc + sh, 0.f); a3.y = fmaxf(a3.y * sc + sh, 0.f);
      a3.z = fmaxf(a3.z * sc + sh, 0.f); a3.w = fmaxf(a3.w * sc + sh, 0.f);
      *(float4*)&s_h2[c3][4 * j3 + 4] = a3;
    }
  }
  if (tid < 8) {
    *(float4*)&s_h2[tid][0] = make_float4(0.f, 0.f, 0.f, 0.f);
    *(float4*)&s_h2[tid][504] = make_float4(0.f, 0.f, 0.f, 0.f);
  }
  __syncthreads();
  // conv3 channel-split over in-LDS h2; pipelined x-reads; SGPR weights;
  // packed channel-pair accumulate
  int og = __builtin_amdgcn_readfirstlane(tid >> 7);  // wave-uniform
  int pt = tid & 127;
  bool valid = pt < 125;                            // 4*125 = 500 exactly
  v2f y3v[4][4];
#pragma unroll
  for (int oo = 0; oo < 4; oo++)
#pragma unroll
    for (int r = 0; r < 4; r++) { y3v[oo][r].x = 0.f; y3v[oo][r].y = 0.f; }
  if (valid) {
    const float4* xp0 = (const float4*)&s_h2[0][4 * pt];
    float4 n0 = xp0[0], n1 = xp0[1], n2 = xp0[2];
#pragma unroll 1
    for (int c = 0; c < 8; c++) {
      float4 d0 = n0, d1 = n1, d2 = n2;
      const float4* xpn = (const float4*)&s_h2[c + 1][4 * pt];  // row8 garbage ok
      n0 = xpn[0]; n1 = xpn[1]; n2 = xpn[2];
      float xr[12];
      xr[0] = d0.x; xr[1] = d0.y; xr[2] = d0.z; xr[3] = d0.w;
      xr[4] = d1.x; xr[5] = d1.y; xr[6] = d1.z; xr[7] = d1.w;
      xr[8] = d2.x; xr[9] = d2.y; xr[10] = d2.z; xr[11] = d2.w;
#pragma unroll
      for (int k = 0; k < 7; k++) {
        float4 w0 = *(const float4*)&w3t[(c * 7 + k) * 16 + og * 8];
        float4 w1v = *(const float4*)&w3t[(c * 7 + k) * 16 + og * 8 + 4];
        v2f wp0, wp1, wp2, wp3;
        wp0.x = w0.x; wp0.y = w0.y;
        wp1.x = w0.z; wp1.y = w0.w;
        wp2.x = w1v.x; wp2.y = w1v.y;
        wp3.x = w1v.z; wp3.y = w1v.w;
#pragma unroll
        for (int r = 0; r < 4; r++) {
          v2f xs; xs.x = xr[r + k + 1]; xs.y = xr[r + k + 1];
          y3v[0][r] += wp0 * xs;
          y3v[1][r] += wp1 * xs;
          y3v[2][r] += wp2 * xs;
          y3v[3][r] += wp3 * xs;
        }
      }
    }
    long yb = (((long)n * BSZ + b) * 16 + og * 8) * 250 + 2 * pt;
#pragma unroll
    for (int oo = 0; oo < 4; oo++) {
      float2 vx, vy;
      vx.x = fmaxf(y3v[oo][0].x, y3v[oo][1].x);
      vx.y = fmaxf(y3v[oo][2].x, y3v[oo][3].x);
      *(float2*)&y3p[yb + (2 * oo) * 250] = vx;
      vy.x = fmaxf(y3v[oo][0].y, y3v[oo][1].y);
      vy.y = fmaxf(y3v[oo][2].y, y3v[oo][3].y);
      *(float2*)&y3p[yb + (2 * oo + 1) * 250] = vy;
    }
  }
  int lane = tid & 63, wv = tid >> 6;
#pragma unroll
  for (int o = 0; o < 8; o++) {
    float g0 = (o & 1) ? y3v[o >> 1][0].y : y3v[o >> 1][0].x;
    float g1 = (o & 1) ? y3v[o >> 1][1].y : y3v[o >> 1][1].x;
    float g2 = (o & 1) ? y3v[o >> 1][2].y : y3v[o >> 1][2].x;
    float g3 = (o & 1) ? y3v[o >> 1][3].y : y3v[o >> 1][3].x;
    float s = g0 + g1 + g2 + g3;
    float q = g0 * g0 + g1 * g1 + g2 * g2 + g3 * g3;
#pragma unroll
    for (int off = 32; off > 0; off >>= 1) {
      s += __shfl_down(s, off, 64);
      q += __shfl_down(q, off, 64);
    }
    if (lane == 0) { s_red[0][wv][o] = s; s_red[1][wv][o] = q; }
  }
  __syncthreads();
  if (tid < 16) {
    int og2 = tid >> 3, o = tid & 7;
    float s = s_red[0][2 * og2][o] + s_red[0][2 * og2 + 1][o];
    float q = s_red[1][2 * og2][o] + s_red[1][2 * og2 + 1][o];
    long slot = (long)n * BSZ + b;
    p3[slot * 32 + tid] = s;
    p3[slot * 32 + 16 + tid] = q;
  }
}

// ---------------------------------------------------------------------------
// F3: BN3 + ReLU + avg over pooled raw conv3 -> feat[b][n][16].
// grid: (1, B, N), block 256 (16 chans x 16 threads). SEPARATE kernel:
// R12 lesson — folding into 256-block graph_head collapses parallelism.
// ---------------------------------------------------------------------------
__global__ __launch_bounds__(256) void feat_apply(
    const float* __restrict__ y3p,
    const float* __restrict__ scs3,
    float* __restrict__ feat) {
  int tid = threadIdx.x, n = blockIdx.z, b = blockIdx.y;
  int ch = tid >> 4, s = tid & 15;
  const float* yb = y3p + (((long)n * BSZ + b) * 16 + ch) * 250;
  float sc = scs3[n * 64 + ch], sh = scs3[n * 64 + 32 + ch];
  float acc = 0.f;
  for (int j = s; j < 125; j += 16) {
    float2 v = *(const float2*)&yb[2 * j];
    acc += fmaxf(v.x * sc + sh, 0.f) + fmaxf(v.y * sc + sh, 0.f);
  }
#pragma unroll
  for (int off = 8; off > 0; off >>= 1) acc += __shfl_down(acc, off, 16);
  if (s == 0) feat[((long)b * NND + n) * 16 + ch] = acc * (1.0f / 250.f);
}

// ---------------------------------------------------------------------------
// Graph tail: adjacency (top-4 incl self) + 3 GCN layers + node-mean + MLP
// grid: (B), block: 256.
// ---------------------------------------------------------------------------
__global__ __launch_bounds__(256) void graph_head(
    const float* __restrict__ feat,
    const float* __restrict__ gw1, const float* __restrict__ gb1,
    const float* __restrict__ gw2, const float* __restrict__ gb2,
    const float* __restrict__ gw3, const float* __restrict__ gb3,
    const float* __restrict__ fw1, const float* __restrict__ fb1,
    const float* __restrict__ fw2, const float* __restrict__ fb2,
    float* __restrict__ out) {
  int b = blockIdx.x, tid = threadIdx.x;
  __shared__ float s_feat[NND][16];
  __shared__ float s_sq[NND];
  __shared__ float s_dist[NND][NND];
  __shared__ float s_adj[NND][NND];
  __shared__ float s_x[NND][128];
  __shared__ float s_t[NND][128];
  __shared__ float s_pool[128];
  __shared__ float s_h[64];
  for (int i = tid; i < NND * 16; i += 256) s_feat[i >> 4][i & 15] = feat[b * NND * 16 + i];
  __syncthreads();
  if (tid < NND) {
    float s = 0.f;
    for (int c = 0; c < 16; c++) s += s_feat[tid][c] * s_feat[tid][c];
    s_sq[tid] = s;
  }
  __syncthreads();
  for (int i = tid; i < NND * NND; i += 256) {
    int nn = i / NND, m = i % NND;
    float d = 0.f;
    for (int c = 0; c < 16; c++) d += s_feat[nn][c] * s_feat[m][c];
    s_dist[nn][m] = s_sq[nn] + s_sq[m] - 2.f * d;  // diagonal exactly 0
    s_adj[nn][m] = 0.f;
  }
  __syncthreads();
  if (tid < NND) {  // top-4 smallest, ties -> earliest index (matches top_k)
    unsigned used = 0;
    for (int j = 0; j < 4; j++) {
      float best = 3.4e38f; int bi = 0;
      for (int m = 0; m < NND; m++)
        if (!((used >> m) & 1u) && s_dist[tid][m] < best) { best = s_dist[tid][m]; bi = m; }
      used |= 1u << bi;
      s_adj[tid][bi] = 0.25f;
    }
  }
  __syncthreads();
  for (int i = tid; i < NND * 32; i += 256) {
    int nn = i / 32, f = i % 32;
    float a = 0.f;
    for (int c = 0; c < 16; c++) a += s_feat[nn][c] * gw1[c * 32 + f];
    s_t[nn][f] = a;
  }
  __syncthreads();
  for (int i = tid; i < NND * 32; i += 256) {
    int nn = i / 32, f = i % 32;
    float a = gb1[f];
    for (int m = 0; m < NND; m++) a += s_adj[nn][m] * s_t[m][f];
    s_x[nn][f] = fmaxf(a, 0.f);
  }
  __syncthreads();
  for (int i = tid; i < NND * 64; i += 256) {
    int nn = i / 64, f = i % 64;
    float a = 0.f;
    for (int c = 0; c < 32; c++) a += s_x[nn][c] * gw2[c * 64 + f];
    s_t[nn][f] = a;
  }
  __syncthreads();
  for (int i = tid; i < NND * 64; i += 256) {
    int nn = i / 64, f = i % 64;
    float a = gb2[f];
    for (int m = 0; m < NND; m++) a += s_adj[nn][m] * s_t[m][f];
    s_x[nn][f] = fmaxf(a, 0.f);
  }
  __syncthreads();
  for (int i = tid; i < NND * 128; i += 256) {
    int nn = i / 128, f = i % 128;
    float a = 0.f;
    for (int c = 0; c < 64; c++) a += s_x[nn][c] * gw3[c * 128 + f];
    s_t[nn][f] = a;
  }
  __syncthreads();
  for (int i = tid; i < NND * 128; i += 256) {
    int nn = i / 128, f = i % 128;
    float a = gb3[f];
    for (int m = 0; m < NND; m++) a += s_adj[nn][m] * s_t[m][f];
    s_x[nn][f] = fmaxf(a, 0.f);
  }
  __syncthreads();
  if (tid < 128) {
    float a = 0.f;
    for (int m = 0; m < NND; m++) a += s_x[m][tid];
    s_pool[tid] = a * (1.0f / (float)NND);
  }
  __syncthreads();
  if (tid < 64) {
    float a = fb1[tid];
    for (int c = 0; c < 128; c++) a += s_pool[c] * fw1[c * 64 + tid];
    s_h[tid] = a;
  }
  __syncthreads();
  if (tid < 4) {
    float a = fb2[tid];
    for (int c = 0; c < 64; c++) a += s_h[c] * fw2[c * 4 + tid];
    out[b * 4 + tid] = a;
  }
}

extern "C" void kernel_launch(void* const* d_in, const int* in_sizes, int n_in,
                              void* d_out, int out_size, void* d_ws, size_t ws_size,
                              hipStream_t stream) {
  (void)in_sizes; (void)n_in; (void)out_size; (void)ws_size;
  const float* x   = (const float*)d_in[0];
  const float* w1  = (const float*)d_in[1];
  const float* g1  = (const float*)d_in[2];
  const float* b1  = (const float*)d_in[3];
  const float* w2  = (const float*)d_in[4];
  const float* g2  = (const float*)d_in[5];
  const float* b2  = (const float*)d_in[6];
  const float* w3  = (const float*)d_in[7];
  const float* g3  = (const float*)d_in[8];
  const float* b3  = (const float*)d_in[9];
  const float* gw1 = (const float*)d_in[10];
  const float* gb1 = (const float*)d_in[11];
  const float* gw2 = (const float*)d_in[12];
  const float* gb2 = (const float*)d_in[13];
  const float* gw3 = (const float*)d_in[14];
  const float* gb3 = (const float*)d_in[15];
  const float* fw1 = (const float*)d_in[16];
  const float* fb1 = (const float*)d_in[17];
  const float* fw2 = (const float*)d_in[18];
  const float* fb2 = (const float*)d_in[19];

  float* ws = (float*)d_ws;
  const long Y2 = (long)NND * BSZ * 8 * 500;    // 22,528,000 floats
  const long Y3 = (long)NND * BSZ * 16 * 250;   // 22,528,000 floats
  float* y2p  = ws;
  float* y3p  = y2p + Y2;
  float* feat = y3p + Y3;                       // B*N*16 = 90,112
  float* scs1 = feat + (long)BSZ * NND * 16;
  float* scs2 = scs1 + NND * 64;
  float* scs3 = scs2 + NND * 64;
  float* p1   = scs3 + NND * 64;                // 22*512 slots * 8
  float* p2   = p1 + (long)NND * 512 * 8;       // 22*256 slots * 16
  float* p3   = p2 + (long)NND * 256 * 16;      // 22*256 slots * 32
  float* w2t  = p3 + (long)NND * 256 * 32;      // 224
  float* w3t  = w2t + 224;                      // 896
  // total ws ~= 181 MB (same budget as prior passing rounds)

  // S1: stats1 over x
  conv_statsR<1, 4, 2000, 256, 2, 4><<<dim3(2, BSZ, NND), dim3(256), 0, stream>>>(
      x, 2000, (long)NND * 2000, 0, w1, p1);
  // reduce1 (+ weight pre-transpose in block 0)
  stats_reduce<4, 512, 2000><<<dim3(NND), dim3(256), 0, stream>>>(
      p1, g1, b1, scs1, w2, w3, w2t, w3t);
  // conv1-apply + conv2 (pooled raw out) + stats2 (fused; h1 stays in LDS)
  fused1<<<dim3(1, BSZ, NND), dim3(256), 0, stream>>>(x, w1, scs1, w2t, y2p, p2);
  stats_reduce<8, 256, 1000><<<dim3(NND), dim3(256), 0, stream>>>(
      p2, g2, b2, scs2, nullptr, nullptr, nullptr, nullptr);
  // BN2-apply + conv3 (pooled raw out) + stats3 (fused; no conv2 recompute)
  fused2<<<dim3(1, BSZ, NND), dim3(256), 0, stream>>>(y2p, scs2, w3t, y3p, p3);
  stats_reduce<16, 256, 500><<<dim3(NND), dim3(256), 0, stream>>>(
      p3, g3, b3, scs3, nullptr, nullptr, nullptr, nullptr);
  // BN3 + ReLU + avg -> feat (separate 5632-block kernel; R12 lesson)
  feat_apply<<<dim3(1, BSZ, NND), dim3(256), 0, stream>>>(y3p, scs3, feat);
  // graph tail
  graph_head<<<dim3(BSZ), dim3(256), 0, stream>>>(
      feat, gw1, gb1, gw2, gb2, gw3, gb3, fw1, fb1, fw2, fb2, (float*)d_out);
}

// Round 16
// 213.159 us; speedup vs baseline: 1.2446x; 1.0033x over previous
//
#include <hip/hip_runtime.h>

#define BSZ 256
#define NND 22
#define BN_EPS 1e-5f

typedef float v2f __attribute__((ext_vector_type(2)));

// Packed fma: lowers to v_pk_fma_f32 (R15 lesson: operator += on v2f emits
// pk_mul+pk_add, NOT contracted -> same instr rate as scalar v_fmac).
__device__ __forceinline__ v2f pkfma(v2f a, v2f b, v2f c) {
  return __builtin_elementwise_fma(a, b, c);
}

// ---------------------------------------------------------------------------
// conv core for CIN<=4 (used by S1 only). c-loop unroll-1 ON PURPOSE
// (R4-R7 lesson): full unroll at CIN>=4 blows VGPR to 164-256.
// ---------------------------------------------------------------------------
template<int CIN, int COUT, int R, int SROW>
__device__ __forceinline__ void conv_coreR(
    const float (*s_in)[SROW], const float* s_w, int tid, float y[COUT][R]) {
#pragma unroll
  for (int o = 0; o < COUT; o++)
#pragma unroll
    for (int r = 0; r < R; r++) y[o][r] = 0.f;
#pragma unroll 1
  for (int c = 0; c < CIN; c++) {
    float xr[R + 6];
    if constexpr (R == 4) {
      const float4* xp = (const float4*)&s_in[c][4 * tid];
      float4 xa = xp[0], xb = xp[1];
      float2 xc = *(const float2*)&s_in[c][4 * tid + 8];
      xr[0] = xa.x; xr[1] = xa.y; xr[2] = xa.z; xr[3] = xa.w;
      xr[4] = xb.x; xr[5] = xb.y; xr[6] = xb.z; xr[7] = xb.w;
      xr[8] = xc.x; xr[9] = xc.y;
    } else {
      const float2* xp = (const float2*)&s_in[c][2 * tid];
      float2 x0 = xp[0], x1 = xp[1], x2 = xp[2], x3 = xp[3];
      xr[0] = x0.x; xr[1] = x0.y; xr[2] = x1.x; xr[3] = x1.y;
      xr[4] = x2.x; xr[5] = x2.y; xr[6] = x3.x; xr[7] = x3.y;
    }
#pragma unroll
    for (int k = 0; k < 7; k++) {
      const float4* wp = (const float4*)&s_w[(c * 7 + k) * COUT];
#pragma unroll
      for (int o4 = 0; o4 < COUT / 4; o4++) {
        float4 wv = wp[o4];
#pragma unroll
        for (int r = 0; r < R; r++) {
          y[4 * o4 + 0][r] += wv.x * xr[r + k];
          y[4 * o4 + 1][r] += wv.y * xr[r + k];
          y[4 * o4 + 2][r] += wv.z * xr[r + k];
          y[4 * o4 + 3][r] += wv.w * xr[r + k];
        }
      }
    }
  }
}

template<int CIN, int COUT, int NTH>
__device__ __forceinline__ void stage_weights(const float* __restrict__ w,
                                              float* s_w, int tid) {
  for (int i = tid; i < CIN * 7 * COUT; i += NTH) {
    int c = i / (7 * COUT), k = (i / COUT) % 7, o = i % COUT;
    s_w[i] = w[(o * CIN + c) * 7 + k];
  }
}

// ---------------------------------------------------------------------------
// S1: stats of conv1 over x -> private partial slot. (proven)
// grid: (2, BSZ, NND), block 256.
// ---------------------------------------------------------------------------
template<int CIN, int COUT, int LIN, int NTH, int NT, int R>
__global__ __launch_bounds__(NTH) void conv_statsR(
    const float* __restrict__ in, long sn, long sb, long sc,
    const float* __restrict__ w, float* __restrict__ part) {
  const int TILE = R * NTH;
  const int SROW = TILE + 8;
  __shared__ alignas(16) float s_in[CIN][SROW];
  __shared__ alignas(16) float s_w[CIN * 7 * COUT];
  __shared__ float s_red[2][NTH / 64][COUT];
  int tid = threadIdx.x, n = blockIdx.z, b = blockIdx.y;
  int t0 = blockIdx.x * TILE;
  const float* base = in + (long)n * sn + (long)b * sb;
  stage_weights<CIN, COUT, NTH>(w, s_w, tid);
  for (int c = 0; c < CIN; c++)
    for (int i = tid; i < TILE + 6; i += NTH) {
      int l = t0 + i - 3;
      s_in[c][i] = (l >= 0 && l < LIN) ? base[(long)c * sc + l] : 0.f;
    }
  __syncthreads();
  float y[COUT][R];
  conv_coreR<CIN, COUT, R, SROW>(s_in, s_w, tid, y);
  bool valid = (t0 + R * tid) < LIN;
  int lane = tid & 63, wv = tid >> 6;
#pragma unroll
  for (int o = 0; o < COUT; o++) {
    float s = 0.f, q = 0.f;
    if (valid) {
#pragma unroll
      for (int r = 0; r < R; r++) { s += y[o][r]; q += y[o][r] * y[o][r]; }
    }
#pragma unroll
    for (int off = 32; off > 0; off >>= 1) {
      s += __shfl_down(s, off, 64);
      q += __shfl_down(q, off, 64);
    }
    if (lane == 0) { s_red[0][wv][o] = s; s_red[1][wv][o] = q; }
  }
  __syncthreads();
  if (tid < COUT) {
    float s = 0.f, q = 0.f;
#pragma unroll
    for (int g = 0; g < NTH / 64; g++) { s += s_red[0][g][tid]; q += s_red[1][g][tid]; }
    long slot = ((long)n * NT + blockIdx.x) * BSZ + b;
    part[slot * (2 * COUT) + tid] = s;
    part[slot * (2 * COUT) + COUT + tid] = q;
  }
}

// ---------------------------------------------------------------------------
// Reduce partials -> BN scale/shift. scs[n*64+o]=scale, scs[n*64+32+o]=shift
// Optionally (w2t != nullptr, block 0) also pre-transposes conv2/conv3
// weights to [c][k][o] global buffers (folded prep launch, R12-verified).
// ---------------------------------------------------------------------------
template<int C, int NSLOT, int LIN>
__global__ __launch_bounds__(256) void stats_reduce(
    const float* __restrict__ part,
    const float* __restrict__ gamma, const float* __restrict__ beta,
    float* __restrict__ scs,
    const float* __restrict__ w2, const float* __restrict__ w3,
    float* __restrict__ w2t, float* __restrict__ w3t) {
  const int V = 2 * C;
  const int GRP = 256 / V;
  int n = blockIdx.x, tid = threadIdx.x;
  int j = tid % V, g = tid / V;
  const float* p = part + (long)n * NSLOT * V;
  float s = 0.f;
  for (int sl = g; sl < NSLOT; sl += GRP) s += p[(long)sl * V + j];
  __shared__ float red[V][GRP];
  __shared__ float tot[V];
  red[j][g] = s;
  __syncthreads();
  if (tid < V) {
    float t = 0.f;
#pragma unroll
    for (int gg = 0; gg < GRP; gg++) t += red[tid][gg];
    tot[tid] = t;
  }
  __syncthreads();
  if (tid < C) {
    float cnt = (float)BSZ * (float)LIN;
    float m = tot[tid] / cnt;
    float var = tot[C + tid] / cnt - m * m;
    float istd = 1.0f / sqrtf(var + BN_EPS);
    float scl = gamma[tid] * istd;
    scs[n * 64 + tid] = scl;
    scs[n * 64 + 32 + tid] = beta[tid] - m * scl;
  }
  if (w2t != nullptr && blockIdx.x == 0) {
    if (tid < 224) {
      int c = tid / 56, k = (tid / 8) % 7, o = tid & 7;
      w2t[tid] = w2[(o * 4 + c) * 7 + k];
    }
    for (int i = tid; i < 896; i += 256) {
      int c = i / 112, k = (i / 16) % 7, o = i & 15;
      w3t[i] = w3[(o * 8 + c) * 7 + k];
    }
  }
}

// ---------------------------------------------------------------------------
// F1: conv1+BN1+ReLU+pool -> h1 (LDS ONLY) -> conv2 -> pooled raw conv2 to
// global (y2p; scale2>0 so maxpool∘relu∘BN == relu∘BN∘maxpool) + stats2
// partials. Inner loops: channel-pair v_pk_fma_f32 via explicit fma builtin.
// grid: (1, B, N), block 256.
// ---------------------------------------------------------------------------
__global__ __launch_bounds__(256) void fused1(
    const float* __restrict__ x,      // (B, N, 2000)
    const float* __restrict__ w1,     // (4,1,7)
    const float* __restrict__ scs1,
    const float* __restrict__ w2t,    // [c][k][o] transposed conv2 weights
    float* __restrict__ y2p,          // [n][b][8][500] pooled raw conv2
    float* __restrict__ p2) {         // [(n*256+b)*16]
  __shared__ alignas(16) float s_x[2016];       // s_x[j+4] = x[j]
  __shared__ alignas(16) float s_h1[5][1008];   // row 4 = garbage prefetch row
  __shared__ float s_sc[4], s_sh[4];
  __shared__ float s_red[2][4][8];
  int tid = threadIdx.x, n = blockIdx.z, b = blockIdx.y;
  const float* xb = x + (long)b * (NND * 2000) + (long)n * 2000;
  if (tid < 4) { s_sc[tid] = scs1[n * 64 + tid]; s_sh[tid] = scs1[n * 64 + 32 + tid]; }
  {  // batched staging: both global loads issued before any LDS write
    float4 a0 = *(const float4*)&xb[4 * tid];
    float4 a1;
    bool m1 = tid + 256 < 500;
    if (m1) a1 = *(const float4*)&xb[4 * (tid + 256)];
    *(float4*)&s_x[4 * tid + 4] = a0;
    if (m1) *(float4*)&s_x[4 * (tid + 256) + 4] = a1;
  }
  if (tid == 0) {
    *(float4*)&s_x[0] = make_float4(0.f, 0.f, 0.f, 0.f);
    *(float4*)&s_x[2004] = make_float4(0.f, 0.f, 0.f, 0.f);
  }
  __syncthreads();
  // ---- Phase A: conv1 (8 pos/thread, 2 channel-pairs) + BN1+ReLU+pool ----
  if (tid < 250) {                                  // 8*250 = 2000 exactly
    float xr[16];
    const float4* xp = (const float4*)&s_x[8 * tid];
#pragma unroll
    for (int v = 0; v < 4; v++) {
      float4 t = xp[v];
      xr[4 * v + 0] = t.x; xr[4 * v + 1] = t.y;
      xr[4 * v + 2] = t.z; xr[4 * v + 3] = t.w;
    }
    v2f yv[2][8];
#pragma unroll
    for (int oo = 0; oo < 2; oo++)
#pragma unroll
      for (int r = 0; r < 8; r++) { yv[oo][r].x = 0.f; yv[oo][r].y = 0.f; }
#pragma unroll
    for (int k = 0; k < 7; k++) {
      v2f wpA, wpB;
      wpA.x = w1[0 * 7 + k]; wpA.y = w1[1 * 7 + k];
      wpB.x = w1[2 * 7 + k]; wpB.y = w1[3 * 7 + k];
#pragma unroll
      for (int r = 0; r < 8; r++) {
        v2f xs; xs.x = xr[r + k + 1]; xs.y = xr[r + k + 1];
        yv[0][r] = pkfma(wpA, xs, yv[0][r]);
        yv[1][r] = pkfma(wpB, xs, yv[1][r]);
      }
    }
#pragma unroll
    for (int oo = 0; oo < 2; oo++) {
      {
        int o = 2 * oo;
        float a0 = yv[oo][0].x * s_sc[o] + s_sh[o], a1 = yv[oo][1].x * s_sc[o] + s_sh[o];
        float a2 = yv[oo][2].x * s_sc[o] + s_sh[o], a3 = yv[oo][3].x * s_sc[o] + s_sh[o];
        float a4 = yv[oo][4].x * s_sc[o] + s_sh[o], a5 = yv[oo][5].x * s_sc[o] + s_sh[o];
        float a6 = yv[oo][6].x * s_sc[o] + s_sh[o], a7 = yv[oo][7].x * s_sc[o] + s_sh[o];
        float4 v;
        v.x = fmaxf(fmaxf(a0, a1), 0.f);
        v.y = fmaxf(fmaxf(a2, a3), 0.f);
        v.z = fmaxf(fmaxf(a4, a5), 0.f);
        v.w = fmaxf(fmaxf(a6, a7), 0.f);
        *(float4*)&s_h1[o][4 * tid + 4] = v;
      }
      {
        int o = 2 * oo + 1;
        float a0 = yv[oo][0].y * s_sc[o] + s_sh[o], a1 = yv[oo][1].y * s_sc[o] + s_sh[o];
        float a2 = yv[oo][2].y * s_sc[o] + s_sh[o], a3 = yv[oo][3].y * s_sc[o] + s_sh[o];
        float a4 = yv[oo][4].y * s_sc[o] + s_sh[o], a5 = yv[oo][5].y * s_sc[o] + s_sh[o];
        float a6 = yv[oo][6].y * s_sc[o] + s_sh[o], a7 = yv[oo][7].y * s_sc[o] + s_sh[o];
        float4 v;
        v.x = fmaxf(fmaxf(a0, a1), 0.f);
        v.y = fmaxf(fmaxf(a2, a3), 0.f);
        v.z = fmaxf(fmaxf(a4, a5), 0.f);
        v.w = fmaxf(fmaxf(a6, a7), 0.f);
        *(float4*)&s_h1[o][4 * tid + 4] = v;
      }
    }
  }
  if (tid < 4) {
    *(float4*)&s_h1[tid][0] = make_float4(0.f, 0.f, 0.f, 0.f);
    *(float4*)&s_h1[tid][1004] = make_float4(0.f, 0.f, 0.f, 0.f);
  }
  __syncthreads();
  // ---- Phase B: conv2 (pipelined x-reads, 4 channel-pairs) ----
  v2f y2v[4][4];
#pragma unroll
  for (int oo = 0; oo < 4; oo++)
#pragma unroll
    for (int r = 0; r < 4; r++) { y2v[oo][r].x = 0.f; y2v[oo][r].y = 0.f; }
  if (tid < 250) {                                  // 4*250 = 1000 exactly
    const float4* xp0 = (const float4*)&s_h1[0][4 * tid];
    float4 n0 = xp0[0], n1 = xp0[1], n2 = xp0[2];
#pragma unroll 1
    for (int c = 0; c < 4; c++) {
      float4 c0 = n0, c1 = n1, c2 = n2;
      const float4* xpn = (const float4*)&s_h1[c + 1][4 * tid];  // row4 garbage ok
      n0 = xpn[0]; n1 = xpn[1]; n2 = xpn[2];
      float xr[12];
      xr[0] = c0.x; xr[1] = c0.y; xr[2] = c0.z; xr[3] = c0.w;
      xr[4] = c1.x; xr[5] = c1.y; xr[6] = c1.z; xr[7] = c1.w;
      xr[8] = c2.x; xr[9] = c2.y; xr[10] = c2.z; xr[11] = c2.w;
#pragma unroll
      for (int k = 0; k < 7; k++) {
        float4 w0 = *(const float4*)&w2t[(c * 7 + k) * 8];       // s_load
        float4 w1v = *(const float4*)&w2t[(c * 7 + k) * 8 + 4];
        v2f wp0, wp1, wp2, wp3;
        wp0.x = w0.x; wp0.y = w0.y;
        wp1.x = w0.z; wp1.y = w0.w;
        wp2.x = w1v.x; wp2.y = w1v.y;
        wp3.x = w1v.z; wp3.y = w1v.w;
#pragma unroll
        for (int r = 0; r < 4; r++) {
          v2f xs; xs.x = xr[r + k + 1]; xs.y = xr[r + k + 1];
          y2v[0][r] = pkfma(wp0, xs, y2v[0][r]);
          y2v[1][r] = pkfma(wp1, xs, y2v[1][r]);
          y2v[2][r] = pkfma(wp2, xs, y2v[2][r]);
          y2v[3][r] = pkfma(wp3, xs, y2v[3][r]);
        }
      }
    }
    long yb = ((long)n * BSZ + b) * 4000 + 2 * tid;
#pragma unroll
    for (int oo = 0; oo < 4; oo++) {
      float2 vx, vy;
      vx.x = fmaxf(y2v[oo][0].x, y2v[oo][1].x);
      vx.y = fmaxf(y2v[oo][2].x, y2v[oo][3].x);
      *(float2*)&y2p[yb + (2 * oo) * 500] = vx;
      vy.x = fmaxf(y2v[oo][0].y, y2v[oo][1].y);
      vy.y = fmaxf(y2v[oo][2].y, y2v[oo][3].y);
      *(float2*)&y2p[yb + (2 * oo + 1) * 500] = vy;
    }
  }
  int lane = tid & 63, wv = tid >> 6;
#pragma unroll
  for (int o = 0; o < 8; o++) {
    float g0 = (o & 1) ? y2v[o >> 1][0].y : y2v[o >> 1][0].x;
    float g1 = (o & 1) ? y2v[o >> 1][1].y : y2v[o >> 1][1].x;
    float g2 = (o & 1) ? y2v[o >> 1][2].y : y2v[o >> 1][2].x;
    float g3 = (o & 1) ? y2v[o >> 1][3].y : y2v[o >> 1][3].x;
    float s = g0 + g1 + g2 + g3;
    float q = g0 * g0 + g1 * g1 + g2 * g2 + g3 * g3;
#pragma unroll
    for (int off = 32; off > 0; off >>= 1) {
      s += __shfl_down(s, off, 64);
      q += __shfl_down(q, off, 64);
    }
    if (lane == 0) { s_red[0][wv][o] = s; s_red[1][wv][o] = q; }
  }
  __syncthreads();
  if (tid < 8) {
    float s = 0.f, q = 0.f;
#pragma unroll
    for (int g = 0; g < 4; g++) { s += s_red[0][g][tid]; q += s_red[1][g][tid]; }
    long slot = (long)n * BSZ + b;
    p2[slot * 16 + tid] = s;
    p2[slot * 16 + 8 + tid] = q;
  }
}

// ---------------------------------------------------------------------------
// F2: read y2p, BN2+ReLU -> h2 in LDS, conv3 (channel-split, pipelined
// x-reads, 4 channel-pairs v_pk_fma) -> pooled raw conv3 (y3p) + stats3
// partials. grid: (1, B, N), block 256.
// ---------------------------------------------------------------------------
__global__ __launch_bounds__(256) void fused2(
    const float* __restrict__ y2p,    // [n][b][8][500]
    const float* __restrict__ scs2,
    const float* __restrict__ w3t,    // [c][k][o] transposed conv3 weights
    float* __restrict__ y3p,          // [n][b][16][250] pooled raw conv3
    float* __restrict__ p3) {         // [(n*256+b)*32]
  __shared__ alignas(16) float s_h2[9][512];    // row 8 = garbage prefetch row
  __shared__ float s_sc[8], s_sh[8];
  __shared__ float s_red[2][4][8];
  int tid = threadIdx.x, n = blockIdx.z, b = blockIdx.y;
  if (tid < 8) { s_sc[tid] = scs2[n * 64 + tid]; s_sh[tid] = scs2[n * 64 + 32 + tid]; }
  __syncthreads();
  // batched staging: 4 global loads issued together, then BN2+ReLU -> s_h2
  const float* yb2 = y2p + ((long)n * BSZ + b) * 4000;
  {
    int i0 = tid, i1 = tid + 256, i2 = tid + 512, i3 = tid + 768;
    int c0 = i0 / 125, j0 = i0 % 125;
    int c1 = i1 / 125, j1 = i1 % 125;
    int c2 = i2 / 125, j2 = i2 % 125;
    int c3 = i3 / 125, j3 = i3 % 125;
    bool m3 = i3 < 1000;
    float4 a0 = *(const float4*)&yb2[c0 * 500 + 4 * j0];
    float4 a1 = *(const float4*)&yb2[c1 * 500 + 4 * j1];
    float4 a2 = *(const float4*)&yb2[c2 * 500 + 4 * j2];
    float4 a3;
    if (m3) a3 = *(const float4*)&yb2[c3 * 500 + 4 * j3];
    float sc, sh;
    sc = s_sc[c0]; sh = s_sh[c0];
    a0.x = fmaxf(a0.x * sc + sh, 0.f); a0.y = fmaxf(a0.y * sc + sh, 0.f);
    a0.z = fmaxf(a0.z * sc + sh, 0.f); a0.w = fmaxf(a0.w * sc + sh, 0.f);
    *(float4*)&s_h2[c0][4 * j0 + 4] = a0;
    sc = s_sc[c1]; sh = s_sh[c1];
    a1.x = fmaxf(a1.x * sc + sh, 0.f); a1.y = fmaxf(a1.y * sc + sh, 0.f);
    a1.z = fmaxf(a1.z * sc + sh, 0.f); a1.w = fmaxf(a1.w * sc + sh, 0.f);
    *(float4*)&s_h2[c1][4 * j1 + 4] = a1;
    sc = s_sc[c2]; sh = s_sh[c2];
    a2.x = fmaxf(a2.x * sc + sh, 0.f); a2.y = fmaxf(a2.y * sc + sh, 0.f);
    a2.z = fmaxf(a2.z * sc + sh, 0.f); a2.w = fmaxf(a2.w * sc + sh, 0.f);
    *(float4*)&s_h2[c2][4 * j2 + 4] = a2;
    if (m3) {
      sc = s_sc[c3]; sh = s_sh[c3];
      a3.x = fmaxf(a3.x * sc + sh, 0.f); a3.y = fmaxf(a3.y * sc + sh, 0.f);
      a3.z = fmaxf(a3.z * sc + sh, 0.f); a3.w = fmaxf(a3.w * sc + sh, 0.f);
      *(float4*)&s_h2[c3][4 * j3 + 4] = a3;
    }
  }
  if (tid < 8) {
    *(float4*)&s_h2[tid][0] = make_float4(0.f, 0.f, 0.f, 0.f);
    *(float4*)&s_h2[tid][504] = make_float4(0.f, 0.f, 0.f, 0.f);
  }
  __syncthreads();
  // conv3 channel-split over in-LDS h2; pipelined x-reads; SGPR weights;
  // packed channel-pair fma
  int og = __builtin_amdgcn_readfirstlane(tid >> 7);  // wave-uniform
  int pt = tid & 127;
  bool valid = pt < 125;                            // 4*125 = 500 exactly
  v2f y3v[4][4];
#pragma unroll
  for (int oo = 0; oo < 4; oo++)
#pragma unroll
    for (int r = 0; r < 4; r++) { y3v[oo][r].x = 0.f; y3v[oo][r].y = 0.f; }
  if (valid) {
    const float4* xp0 = (const float4*)&s_h2[0][4 * pt];
    float4 n0 = xp0[0], n1 = xp0[1], n2 = xp0[2];
#pragma unroll 1
    for (int c = 0; c < 8; c++) {
      float4 d0 = n0, d1 = n1, d2 = n2;
      const float4* xpn = (const float4*)&s_h2[c + 1][4 * pt];  // row8 garbage ok
      n0 = xpn[0]; n1 = xpn[1]; n2 = xpn[2];
      float xr[12];
      xr[0] = d0.x; xr[1] = d0.y; xr[2] = d0.z; xr[3] = d0.w;
      xr[4] = d1.x; xr[5] = d1.y; xr[6] = d1.z; xr[7] = d1.w;
      xr[8] = d2.x; xr[9] = d2.y; xr[10] = d2.z; xr[11] = d2.w;
#pragma unroll
      for (int k = 0; k < 7; k++) {
        float4 w0 = *(const float4*)&w3t[(c * 7 + k) * 16 + og * 8];
        float4 w1v = *(const float4*)&w3t[(c * 7 + k) * 16 + og * 8 + 4];
        v2f wp0, wp1, wp2, wp3;
        wp0.x = w0.x; wp0.y = w0.y;
        wp1.x = w0.z; wp1.y = w0.w;
        wp2.x = w1v.x; wp2.y = w1v.y;
        wp3.x = w1v.z; wp3.y = w1v.w;
#pragma unroll
        for (int r = 0; r < 4; r++) {
          v2f xs; xs.x = xr[r + k + 1]; xs.y = xr[r + k + 1];
          y3v[0][r] = pkfma(wp0, xs, y3v[0][r]);
          y3v[1][r] = pkfma(wp1, xs, y3v[1][r]);
          y3v[2][r] = pkfma(wp2, xs, y3v[2][r]);
          y3v[3][r] = pkfma(wp3, xs, y3v[3][r]);
        }
      }
    }
    long yb = (((long)n * BSZ + b) * 16 + og * 8) * 250 + 2 * pt;
#pragma unroll
    for (int oo = 0; oo < 4; oo++) {
      float2 vx, vy;
      vx.x = fmaxf(y3v[oo][0].x, y3v[oo][1].x);
      vx.y = fmaxf(y3v[oo][2].x, y3v[oo][3].x);
      *(float2*)&y3p[yb + (2 * oo) * 250] = vx;
      vy.x = fmaxf(y3v[oo][0].y, y3v[oo][1].y);
      vy.y = fmaxf(y3v[oo][2].y, y3v[oo][3].y);
      *(float2*)&y3p[yb + (2 * oo + 1) * 250] = vy;
    }
  }
  int lane = tid & 63, wv = tid >> 6;
#pragma unroll
  for (int o = 0; o < 8; o++) {
    float g0 = (o & 1) ? y3v[o >> 1][0].y : y3v[o >> 1][0].x;
    float g1 = (o & 1) ? y3v[o >> 1][1].y : y3v[o >> 1][1].x;
    float g2 = (o & 1) ? y3v[o >> 1][2].y : y3v[o >> 1][2].x;
    float g3 = (o & 1) ? y3v[o >> 1][3].y : y3v[o >> 1][3].x;
    float s = g0 + g1 + g2 + g3;
    float q = g0 * g0 + g1 * g1 + g2 * g2 + g3 * g3;
#pragma unroll
    for (int off = 32; off > 0; off >>= 1) {
      s += __shfl_down(s, off, 64);
      q += __shfl_down(q, off, 64);
    }
    if (lane == 0) { s_red[0][wv][o] = s; s_red[1][wv][o] = q; }
  }
  __syncthreads();
  if (tid < 16) {
    int og2 = tid >> 3, o = tid & 7;
    float s = s_red[0][2 * og2][o] + s_red[0][2 * og2 + 1][o];
    float q = s_red[1][2 * og2][o] + s_red[1][2 * og2 + 1][o];
    long slot = (long)n * BSZ + b;
    p3[slot * 32 + tid] = s;
    p3[slot * 32 + 16 + tid] = q;
  }
}

// ---------------------------------------------------------------------------
// F3: BN3 + ReLU + avg over pooled raw conv3 -> feat[b][n][16].
// grid: (1, B, N), block 256 (16 chans x 16 threads). SEPARATE kernel:
// R12 lesson — folding into 256-block graph_head collapses parallelism.
// ---------------------------------------------------------------------------
__global__ __launch_bounds__(256) void feat_apply(
    const float* __restrict__ y3p,
    const float* __restrict__ scs3,
    float* __restrict__ feat) {
  int tid = threadIdx.x, n = blockIdx.z, b = blockIdx.y;
  int ch = tid >> 4, s = tid & 15;
  const float* yb = y3p + (((long)n * BSZ + b) * 16 + ch) * 250;
  float sc = scs3[n * 64 + ch], sh = scs3[n * 64 + 32 + ch];
  float acc = 0.f;
  for (int j = s; j < 125; j += 16) {
    float2 v = *(const float2*)&yb[2 * j];
    acc += fmaxf(v.x * sc + sh, 0.f) + fmaxf(v.y * sc + sh, 0.f);
  }
#pragma unroll
  for (int off = 8; off > 0; off >>= 1) acc += __shfl_down(acc, off, 16);
  if (s == 0) feat[((long)b * NND + n) * 16 + ch] = acc * (1.0f / 250.f);
}

// ---------------------------------------------------------------------------
// Graph tail: adjacency (top-4 incl self) + 3 GCN layers + node-mean + MLP
// grid: (B), block: 256.
// ---------------------------------------------------------------------------
__global__ __launch_bounds__(256) void graph_head(
    const float* __restrict__ feat,
    const float* __restrict__ gw1, const float* __restrict__ gb1,
    const float* __restrict__ gw2, const float* __restrict__ gb2,
    const float* __restrict__ gw3, const float* __restrict__ gb3,
    const float* __restrict__ fw1, const float* __restrict__ fb1,
    const float* __restrict__ fw2, const float* __restrict__ fb2,
    float* __restrict__ out) {
  int b = blockIdx.x, tid = threadIdx.x;
  __shared__ float s_feat[NND][16];
  __shared__ float s_sq[NND];
  __shared__ float s_dist[NND][NND];
  __shared__ float s_adj[NND][NND];
  __shared__ float s_x[NND][128];
  __shared__ float s_t[NND][128];
  __shared__ float s_pool[128];
  __shared__ float s_h[64];
  for (int i = tid; i < NND * 16; i += 256) s_feat[i >> 4][i & 15] = feat[b * NND * 16 + i];
  __syncthreads();
  if (tid < NND) {
    float s = 0.f;
    for (int c = 0; c < 16; c++) s += s_feat[tid][c] * s_feat[tid][c];
    s_sq[tid] = s;
  }
  __syncthreads();
  for (int i = tid; i < NND * NND; i += 256) {
    int nn = i / NND, m = i % NND;
    float d = 0.f;
    for (int c = 0; c < 16; c++) d += s_feat[nn][c] * s_feat[m][c];
    s_dist[nn][m] = s_sq[nn] + s_sq[m] - 2.f * d;  // diagonal exactly 0
    s_adj[nn][m] = 0.f;
  }
  __syncthreads();
  if (tid < NND) {  // top-4 smallest, ties -> earliest index (matches top_k)
    unsigned used = 0;
    for (int j = 0; j < 4; j++) {
      float best = 3.4e38f; int bi = 0;
      for (int m = 0; m < NND; m++)
        if (!((used >> m) & 1u) && s_dist[tid][m] < best) { best = s_dist[tid][m]; bi = m; }
      used |= 1u << bi;
      s_adj[tid][bi] = 0.25f;
    }
  }
  __syncthreads();
  for (int i = tid; i < NND * 32; i += 256) {
    int nn = i / 32, f = i % 32;
    float a = 0.f;
    for (int c = 0; c < 16; c++) a += s_feat[nn][c] * gw1[c * 32 + f];
    s_t[nn][f] = a;
  }
  __syncthreads();
  for (int i = tid; i < NND * 32; i += 256) {
    int nn = i / 32, f = i % 32;
    float a = gb1[f];
    for (int m = 0; m < NND; m++) a += s_adj[nn][m] * s_t[m][f];
    s_x[nn][f] = fmaxf(a, 0.f);
  }
  __syncthreads();
  for (int i = tid; i < NND * 64; i += 256) {
    int nn = i / 64, f = i % 64;
    float a = 0.f;
    for (int c = 0; c < 32; c++) a += s_x[nn][c] * gw2[c * 64 + f];
    s_t[nn][f] = a;
  }
  __syncthreads();
  for (int i = tid; i < NND * 64; i += 256) {
    int nn = i / 64, f = i % 64;
    float a = gb2[f];
    for (int m = 0; m < NND; m++) a += s_adj[nn][m] * s_t[m][f];
    s_x[nn][f] = fmaxf(a, 0.f);
  }
  __syncthreads();
  for (int i = tid; i < NND * 128; i += 256) {
    int nn = i / 128, f = i % 128;
    float a = 0.f;
    for (int c = 0; c < 64; c++) a += s_x[nn][c] * gw3[c * 128 + f];
    s_t[nn][f] = a;
  }
  __syncthreads();
  for (int i = tid; i < NND * 128; i += 256) {
    int nn = i / 128, f = i % 128;
    float a = gb3[f];
    for (int m = 0; m < NND; m++) a += s_adj[nn][m] * s_t[m][f];
    s_x[nn][f] = fmaxf(a, 0.f);
  }
  __syncthreads();
  if (tid < 128) {
    float a = 0.f;
    for (int m = 0; m < NND; m++) a += s_x[m][tid];
    s_pool[tid] = a * (1.0f / (float)NND);
  }
  __syncthreads();
  if (tid < 64) {
    float a = fb1[tid];
    for (int c = 0; c < 128; c++) a += s_pool[c] * fw1[c * 64 + tid];
    s_h[tid] = a;
  }
  __syncthreads();
  if (tid < 4) {
    float a = fb2[tid];
    for (int c = 0; c < 64; c++) a += s_h[c] * fw2[c * 4 + tid];
    out[b * 4 + tid] = a;
  }
}

extern "C" void kernel_launch(void* const* d_in, const int* in_sizes, int n_in,
                              void* d_out, int out_size, void* d_ws, size_t ws_size,
                              hipStream_t stream) {
  (void)in_sizes; (void)n_in; (void)out_size; (void)ws_size;
  const float* x   = (const float*)d_in[0];
  const float* w1  = (const float*)d_in[1];
  const float* g1  = (const float*)d_in[2];
  const float* b1  = (const float*)d_in[3];
  const float* w2  = (const float*)d_in[4];
  const float* g2  = (const float*)d_in[5];
  const float* b2  = (const float*)d_in[6];
  const float* w3  = (const float*)d_in[7];
  const float* g3  = (const float*)d_in[8];
  const float* b3  = (const float*)d_in[9];
  const float* gw1 = (const float*)d_in[10];
  const float* gb1 = (const float*)d_in[11];
  const float* gw2 = (const float*)d_in[12];
  const float* gb2 = (const float*)d_in[13];
  const float* gw3 = (const float*)d_in[14];
  const float* gb3 = (const float*)d_in[15];
  const float* fw1 = (const float*)d_in[16];
  const float* fb1 = (const float*)d_in[17];
  const float* fw2 = (const float*)d_in[18];
  const float* fb2 = (const float*)d_in[19];

  float* ws = (float*)d_ws;
  const long Y2 = (long)NND * BSZ * 8 * 500;    // 22,528,000 floats
  const long Y3 = (long)NND * BSZ * 16 * 250;   // 22,528,000 floats
  float* y2p  = ws;
  float* y3p  = y2p + Y2;
  float* feat = y3p + Y3;                       // B*N*16 = 90,112
  float* scs1 = feat + (long)BSZ * NND * 16;
  float* scs2 = scs1 + NND * 64;
  float* scs3 = scs2 + NND * 64;
  float* p1   = scs3 + NND * 64;                // 22*512 slots * 8
  float* p2   = p1 + (long)NND * 512 * 8;       // 22*256 slots * 16
  float* p3   = p2 + (long)NND * 256 * 16;      // 22*256 slots * 32
  float* w2t  = p3 + (long)NND * 256 * 32;      // 224
  float* w3t  = w2t + 224;                      // 896
  // total ws ~= 181 MB (same budget as prior passing rounds)

  // S1: stats1 over x
  conv_statsR<1, 4, 2000, 256, 2, 4><<<dim3(2, BSZ, NND), dim3(256), 0, stream>>>(
      x, 2000, (long)NND * 2000, 0, w1, p1);
  // reduce1 (+ weight pre-transpose in block 0)
  stats_reduce<4, 512, 2000><<<dim3(NND), dim3(256), 0, stream>>>(
      p1, g1, b1, scs1, w2, w3, w2t, w3t);
  // conv1-apply + conv2 (pooled raw out) + stats2 (fused; h1 stays in LDS)
  fused1<<<dim3(1, BSZ, NND), dim3(256), 0, stream>>>(x, w1, scs1, w2t, y2p, p2);
  stats_reduce<8, 256, 1000><<<dim3(NND), dim3(256), 0, stream>>>(
      p2, g2, b2, scs2, nullptr, nullptr, nullptr, nullptr);
  // BN2-apply + conv3 (pooled raw out) + stats3 (fused; no conv2 recompute)
  fused2<<<dim3(1, BSZ, NND), dim3(256), 0, stream>>>(y2p, scs2, w3t, y3p, p3);
  stats_reduce<16, 256, 500><<<dim3(NND), dim3(256), 0, stream>>>(
      p3, g3, b3, scs3, nullptr, nullptr, nullptr, nullptr);
  // BN3 + ReLU + avg -> feat (separate 5632-block kernel; R12 lesson)
  feat_apply<<<dim3(1, BSZ, NND), dim3(256), 0, stream>>>(y3p, scs3, feat);
  // graph tail
  graph_head<<<dim3(BSZ), dim3(256), 0, stream>>>(
      feat, gw1, gb1, gw2, gb2, gw3, gb3, fw1, fb1, fw2, fb2, (float*)d_out);
}

// Round 17
// 208.229 us; speedup vs baseline: 1.2740x; 1.0237x over previous
//
#include <hip/hip_runtime.h>

#define BSZ 256
#define NND 22
#define BN_EPS 1e-5f

typedef float v2f __attribute__((ext_vector_type(2)));

__device__ __forceinline__ v2f pkfma(v2f a, v2f b, v2f c) {
  return __builtin_elementwise_fma(a, b, c);
}

// ---------------------------------------------------------------------------
// conv core for CIN<=4 (used by S1 only). c-loop unroll-1 ON PURPOSE
// (R4-R7 lesson): full unroll at CIN>=4 blows VGPR to 164-256.
// ---------------------------------------------------------------------------
template<int CIN, int COUT, int R, int SROW>
__device__ __forceinline__ void conv_coreR(
    const float (*s_in)[SROW], const float* s_w, int tid, float y[COUT][R]) {
#pragma unroll
  for (int o = 0; o < COUT; o++)
#pragma unroll
    for (int r = 0; r < R; r++) y[o][r] = 0.f;
#pragma unroll 1
  for (int c = 0; c < CIN; c++) {
    float xr[R + 6];
    if constexpr (R == 4) {
      const float4* xp = (const float4*)&s_in[c][4 * tid];
      float4 xa = xp[0], xb = xp[1];
      float2 xc = *(const float2*)&s_in[c][4 * tid + 8];
      xr[0] = xa.x; xr[1] = xa.y; xr[2] = xa.z; xr[3] = xa.w;
      xr[4] = xb.x; xr[5] = xb.y; xr[6] = xb.z; xr[7] = xb.w;
      xr[8] = xc.x; xr[9] = xc.y;
    } else {
      const float2* xp = (const float2*)&s_in[c][2 * tid];
      float2 x0 = xp[0], x1 = xp[1], x2 = xp[2], x3 = xp[3];
      xr[0] = x0.x; xr[1] = x0.y; xr[2] = x1.x; xr[3] = x1.y;
      xr[4] = x2.x; xr[5] = x2.y; xr[6] = x3.x; xr[7] = x3.y;
    }
#pragma unroll
    for (int k = 0; k < 7; k++) {
      const float4* wp = (const float4*)&s_w[(c * 7 + k) * COUT];
#pragma unroll
      for (int o4 = 0; o4 < COUT / 4; o4++) {
        float4 wv = wp[o4];
#pragma unroll
        for (int r = 0; r < R; r++) {
          y[4 * o4 + 0][r] += wv.x * xr[r + k];
          y[4 * o4 + 1][r] += wv.y * xr[r + k];
          y[4 * o4 + 2][r] += wv.z * xr[r + k];
          y[4 * o4 + 3][r] += wv.w * xr[r + k];
        }
      }
    }
  }
}

template<int CIN, int COUT, int NTH>
__device__ __forceinline__ void stage_weights(const float* __restrict__ w,
                                              float* s_w, int tid) {
  for (int i = tid; i < CIN * 7 * COUT; i += NTH) {
    int c = i / (7 * COUT), k = (i / COUT) % 7, o = i % COUT;
    s_w[i] = w[(o * CIN + c) * 7 + k];
  }
}

// ---------------------------------------------------------------------------
// S1: stats of conv1 over x -> private partial slot. (proven)
// grid: (2, BSZ, NND), block 256.
// ---------------------------------------------------------------------------
template<int CIN, int COUT, int LIN, int NTH, int NT, int R>
__global__ __launch_bounds__(NTH) void conv_statsR(
    const float* __restrict__ in, long sn, long sb, long sc,
    const float* __restrict__ w, float* __restrict__ part) {
  const int TILE = R * NTH;
  const int SROW = TILE + 8;
  __shared__ alignas(16) float s_in[CIN][SROW];
  __shared__ alignas(16) float s_w[CIN * 7 * COUT];
  __shared__ float s_red[2][NTH / 64][COUT];
  int tid = threadIdx.x, n = blockIdx.z, b = blockIdx.y;
  int t0 = blockIdx.x * TILE;
  const float* base = in + (long)n * sn + (long)b * sb;
  stage_weights<CIN, COUT, NTH>(w, s_w, tid);
  for (int c = 0; c < CIN; c++)
    for (int i = tid; i < TILE + 6; i += NTH) {
      int l = t0 + i - 3;
      s_in[c][i] = (l >= 0 && l < LIN) ? base[(long)c * sc + l] : 0.f;
    }
  __syncthreads();
  float y[COUT][R];
  conv_coreR<CIN, COUT, R, SROW>(s_in, s_w, tid, y);
  bool valid = (t0 + R * tid) < LIN;
  int lane = tid & 63, wv = tid >> 6;
#pragma unroll
  for (int o = 0; o < COUT; o++) {
    float s = 0.f, q = 0.f;
    if (valid) {
#pragma unroll
      for (int r = 0; r < R; r++) { s += y[o][r]; q += y[o][r] * y[o][r]; }
    }
#pragma unroll
    for (int off = 32; off > 0; off >>= 1) {
      s += __shfl_down(s, off, 64);
      q += __shfl_down(q, off, 64);
    }
    if (lane == 0) { s_red[0][wv][o] = s; s_red[1][wv][o] = q; }
  }
  __syncthreads();
  if (tid < COUT) {
    float s = 0.f, q = 0.f;
#pragma unroll
    for (int g = 0; g < NTH / 64; g++) { s += s_red[0][g][tid]; q += s_red[1][g][tid]; }
    long slot = ((long)n * NT + blockIdx.x) * BSZ + b;
    part[slot * (2 * COUT) + tid] = s;
    part[slot * (2 * COUT) + COUT + tid] = q;
  }
}

// ---------------------------------------------------------------------------
// Reduce partials -> BN scale/shift. scs[n*64+o]=scale, scs[n*64+32+o]=shift
// Optionally (w2t != nullptr, block 0) also pre-transposes conv2/conv3
// weights to [c][k][o] global buffers (folded prep launch, R12-verified).
// ---------------------------------------------------------------------------
template<int C, int NSLOT, int LIN>
__global__ __launch_bounds__(256) void stats_reduce(
    const float* __restrict__ part,
    const float* __restrict__ gamma, const float* __restrict__ beta,
    float* __restrict__ scs,
    const float* __restrict__ w2, const float* __restrict__ w3,
    float* __restrict__ w2t, float* __restrict__ w3t) {
  const int V = 2 * C;
  const int GRP = 256 / V;
  int n = blockIdx.x, tid = threadIdx.x;
  int j = tid % V, g = tid / V;
  const float* p = part + (long)n * NSLOT * V;
  float s = 0.f;
  for (int sl = g; sl < NSLOT; sl += GRP) s += p[(long)sl * V + j];
  __shared__ float red[V][GRP];
  __shared__ float tot[V];
  red[j][g] = s;
  __syncthreads();
  if (tid < V) {
    float t = 0.f;
#pragma unroll
    for (int gg = 0; gg < GRP; gg++) t += red[tid][gg];
    tot[tid] = t;
  }
  __syncthreads();
  if (tid < C) {
    float cnt = (float)BSZ * (float)LIN;
    float m = tot[tid] / cnt;
    float var = tot[C + tid] / cnt - m * m;
    float istd = 1.0f / sqrtf(var + BN_EPS);
    float scl = gamma[tid] * istd;
    scs[n * 64 + tid] = scl;
    scs[n * 64 + 32 + tid] = beta[tid] - m * scl;
  }
  if (w2t != nullptr && blockIdx.x == 0) {
    if (tid < 224) {
      int c = tid / 56, k = (tid / 8) % 7, o = tid & 7;
      w2t[tid] = w2[(o * 4 + c) * 7 + k];
    }
    for (int i = tid; i < 896; i += 256) {
      int c = i / 112, k = (i / 16) % 7, o = i & 15;
      w3t[i] = w3[(o * 8 + c) * 7 + k];
    }
  }
}

// ---------------------------------------------------------------------------
// F1: conv1 phase reads x DIRECTLY from global (no s_x LDS, no staging
// barrier; neighbor-overlap served by L1; boundary zeros via 2-lane masks
// with clamped addresses) -> h1 into LDS -> conv2 -> pooled raw y2p +
// stats2 partials. grid: (1, B, N), block 256.
// ---------------------------------------------------------------------------
__global__ __launch_bounds__(256) void fused1(
    const float* __restrict__ x,      // (B, N, 2000)
    const float* __restrict__ w1,     // (4,1,7)
    const float* __restrict__ scs1,
    const float* __restrict__ w2t,    // [c][k][o] transposed conv2 weights
    float* __restrict__ y2p,          // [n][b][8][500] pooled raw conv2
    float* __restrict__ p2) {         // [(n*256+b)*16]
  __shared__ alignas(16) float s_h1[5][1008];   // row 4 = garbage prefetch row
  __shared__ float s_red[2][4][8];
  int tid = threadIdx.x, n = blockIdx.z, b = blockIdx.y;
  const float* xb = x + (long)b * (NND * 2000) + (long)n * 2000;
  // ---- Phase A: conv1 direct-from-global (8 pos/thread) + BN1+ReLU+pool ----
  if (tid < 250) {                                  // 8*250 = 2000 exactly
    bool t0 = (tid == 0), tE = (tid == 249);
    float4 A = *(const float4*)&xb[t0 ? 0 : 8 * tid - 4];   // clamped
    float4 B = *(const float4*)&xb[8 * tid];
    float4 C = *(const float4*)&xb[8 * tid + 4];
    float4 D = *(const float4*)&xb[tE ? 1996 : 8 * tid + 8];  // clamped
    float xr[16];
    xr[0] = A.x; xr[1] = A.y; xr[2] = A.z; xr[3] = A.w;
    xr[4] = B.x; xr[5] = B.y; xr[6] = B.z; xr[7] = B.w;
    xr[8] = C.x; xr[9] = C.y; xr[10] = C.z; xr[11] = C.w;
    xr[12] = D.x; xr[13] = D.y; xr[14] = D.z; xr[15] = D.w;
    if (t0) { xr[1] = 0.f; xr[2] = 0.f; xr[3] = 0.f; }        // x[-3..-1]
    if (tE) { xr[12] = 0.f; xr[13] = 0.f; xr[14] = 0.f; }     // x[2000..2002]
    v2f yv[2][8];
#pragma unroll
    for (int oo = 0; oo < 2; oo++)
#pragma unroll
      for (int r = 0; r < 8; r++) { yv[oo][r].x = 0.f; yv[oo][r].y = 0.f; }
#pragma unroll
    for (int k = 0; k < 7; k++) {
      v2f wpA, wpB;
      wpA.x = w1[0 * 7 + k]; wpA.y = w1[1 * 7 + k];
      wpB.x = w1[2 * 7 + k]; wpB.y = w1[3 * 7 + k];
#pragma unroll
      for (int r = 0; r < 8; r++) {
        v2f xs; xs.x = xr[r + k + 1]; xs.y = xr[r + k + 1];
        yv[0][r] = pkfma(wpA, xs, yv[0][r]);
        yv[1][r] = pkfma(wpB, xs, yv[1][r]);
      }
    }
    // scale/shift via uniform global loads (compile-time o index -> s_load)
    float sc[4], sh[4];
#pragma unroll
    for (int o = 0; o < 4; o++) {
      sc[o] = scs1[n * 64 + o];
      sh[o] = scs1[n * 64 + 32 + o];
    }
#pragma unroll
    for (int oo = 0; oo < 2; oo++) {
      {
        int o = 2 * oo;
        float a0 = yv[oo][0].x * sc[o] + sh[o], a1 = yv[oo][1].x * sc[o] + sh[o];
        float a2 = yv[oo][2].x * sc[o] + sh[o], a3 = yv[oo][3].x * sc[o] + sh[o];
        float a4 = yv[oo][4].x * sc[o] + sh[o], a5 = yv[oo][5].x * sc[o] + sh[o];
        float a6 = yv[oo][6].x * sc[o] + sh[o], a7 = yv[oo][7].x * sc[o] + sh[o];
        float4 v;
        v.x = fmaxf(fmaxf(a0, a1), 0.f);
        v.y = fmaxf(fmaxf(a2, a3), 0.f);
        v.z = fmaxf(fmaxf(a4, a5), 0.f);
        v.w = fmaxf(fmaxf(a6, a7), 0.f);
        *(float4*)&s_h1[o][4 * tid + 4] = v;
      }
      {
        int o = 2 * oo + 1;
        float a0 = yv[oo][0].y * sc[o] + sh[o], a1 = yv[oo][1].y * sc[o] + sh[o];
        float a2 = yv[oo][2].y * sc[o] + sh[o], a3 = yv[oo][3].y * sc[o] + sh[o];
        float a4 = yv[oo][4].y * sc[o] + sh[o], a5 = yv[oo][5].y * sc[o] + sh[o];
        float a6 = yv[oo][6].y * sc[o] + sh[o], a7 = yv[oo][7].y * sc[o] + sh[o];
        float4 v;
        v.x = fmaxf(fmaxf(a0, a1), 0.f);
        v.y = fmaxf(fmaxf(a2, a3), 0.f);
        v.z = fmaxf(fmaxf(a4, a5), 0.f);
        v.w = fmaxf(fmaxf(a6, a7), 0.f);
        *(float4*)&s_h1[o][4 * tid + 4] = v;
      }
    }
  }
  if (tid < 4) {
    *(float4*)&s_h1[tid][0] = make_float4(0.f, 0.f, 0.f, 0.f);
    *(float4*)&s_h1[tid][1004] = make_float4(0.f, 0.f, 0.f, 0.f);
  }
  __syncthreads();
  // ---- Phase B: conv2 (pipelined LDS x-reads, 4 channel-pairs) ----
  v2f y2v[4][4];
#pragma unroll
  for (int oo = 0; oo < 4; oo++)
#pragma unroll
    for (int r = 0; r < 4; r++) { y2v[oo][r].x = 0.f; y2v[oo][r].y = 0.f; }
  if (tid < 250) {                                  // 4*250 = 1000 exactly
    const float4* xp0 = (const float4*)&s_h1[0][4 * tid];
    float4 n0 = xp0[0], n1 = xp0[1], n2 = xp0[2];
#pragma unroll 1
    for (int c = 0; c < 4; c++) {
      float4 c0 = n0, c1 = n1, c2 = n2;
      const float4* xpn = (const float4*)&s_h1[c + 1][4 * tid];  // row4 garbage ok
      n0 = xpn[0]; n1 = xpn[1]; n2 = xpn[2];
      float xr[12];
      xr[0] = c0.x; xr[1] = c0.y; xr[2] = c0.z; xr[3] = c0.w;
      xr[4] = c1.x; xr[5] = c1.y; xr[6] = c1.z; xr[7] = c1.w;
      xr[8] = c2.x; xr[9] = c2.y; xr[10] = c2.z; xr[11] = c2.w;
#pragma unroll
      for (int k = 0; k < 7; k++) {
        float4 w0 = *(const float4*)&w2t[(c * 7 + k) * 8];       // s_load
        float4 w1v = *(const float4*)&w2t[(c * 7 + k) * 8 + 4];
        v2f wp0, wp1, wp2, wp3;
        wp0.x = w0.x; wp0.y = w0.y;
        wp1.x = w0.z; wp1.y = w0.w;
        wp2.x = w1v.x; wp2.y = w1v.y;
        wp3.x = w1v.z; wp3.y = w1v.w;
#pragma unroll
        for (int r = 0; r < 4; r++) {
          v2f xs; xs.x = xr[r + k + 1]; xs.y = xr[r + k + 1];
          y2v[0][r] = pkfma(wp0, xs, y2v[0][r]);
          y2v[1][r] = pkfma(wp1, xs, y2v[1][r]);
          y2v[2][r] = pkfma(wp2, xs, y2v[2][r]);
          y2v[3][r] = pkfma(wp3, xs, y2v[3][r]);
        }
      }
    }
    long yb = ((long)n * BSZ + b) * 4000 + 2 * tid;
#pragma unroll
    for (int oo = 0; oo < 4; oo++) {
      float2 vx, vy;
      vx.x = fmaxf(y2v[oo][0].x, y2v[oo][1].x);
      vx.y = fmaxf(y2v[oo][2].x, y2v[oo][3].x);
      *(float2*)&y2p[yb + (2 * oo) * 500] = vx;
      vy.x = fmaxf(y2v[oo][0].y, y2v[oo][1].y);
      vy.y = fmaxf(y2v[oo][2].y, y2v[oo][3].y);
      *(float2*)&y2p[yb + (2 * oo + 1) * 500] = vy;
    }
  }
  int lane = tid & 63, wv = tid >> 6;
#pragma unroll
  for (int o = 0; o < 8; o++) {
    float g0 = (o & 1) ? y2v[o >> 1][0].y : y2v[o >> 1][0].x;
    float g1 = (o & 1) ? y2v[o >> 1][1].y : y2v[o >> 1][1].x;
    float g2 = (o & 1) ? y2v[o >> 1][2].y : y2v[o >> 1][2].x;
    float g3 = (o & 1) ? y2v[o >> 1][3].y : y2v[o >> 1][3].x;
    float s = g0 + g1 + g2 + g3;
    float q = g0 * g0 + g1 * g1 + g2 * g2 + g3 * g3;
#pragma unroll
    for (int off = 32; off > 0; off >>= 1) {
      s += __shfl_down(s, off, 64);
      q += __shfl_down(q, off, 64);
    }
    if (lane == 0) { s_red[0][wv][o] = s; s_red[1][wv][o] = q; }
  }
  __syncthreads();
  if (tid < 8) {
    float s = 0.f, q = 0.f;
#pragma unroll
    for (int g = 0; g < 4; g++) { s += s_red[0][g][tid]; q += s_red[1][g][tid]; }
    long slot = (long)n * BSZ + b;
    p2[slot * 16 + tid] = s;
    p2[slot * 16 + 8 + tid] = q;
  }
}

// ---------------------------------------------------------------------------
// F2: conv3 DIRECT-FROM-GLOBAL — no h2 LDS, no staging phase, no pre-compute
// barriers. Per c-iteration: 3 coalesced float4 loads from y2p (prefetched
// one c ahead), BN2+ReLU in registers (scale/shift via uniform s_load),
// boundary zeros on lanes pt==0/124 (clamped addrs stay in-buffer).
// -> pooled raw conv3 (y3p) + stats3 partials. grid: (1, B, N), block 256.
// ---------------------------------------------------------------------------
__global__ __launch_bounds__(256) void fused2(
    const float* __restrict__ y2p,    // [n][b][8][500]
    const float* __restrict__ scs2,
    const float* __restrict__ w3t,    // [c][k][o] transposed conv3 weights
    float* __restrict__ y3p,          // [n][b][16][250] pooled raw conv3
    float* __restrict__ p3) {         // [(n*256+b)*32]
  __shared__ float s_red[2][4][8];
  int tid = threadIdx.x, n = blockIdx.z, b = blockIdx.y;
  int og = __builtin_amdgcn_readfirstlane(tid >> 7);  // wave-uniform
  int pt = tid & 127;
  bool valid = pt < 125;                            // 4*125 = 500 exactly
  v2f y3v[4][4];
#pragma unroll
  for (int oo = 0; oo < 4; oo++)
#pragma unroll
    for (int r = 0; r < 4; r++) { y3v[oo][r].x = 0.f; y3v[oo][r].y = 0.f; }
  if (valid) {
    const float* yrow = y2p + ((long)n * BSZ + b) * 4000;
    bool p0 = (pt == 0), pE = (pt == 124);
    int offA = p0 ? 0 : 4 * pt - 4;                 // clamped (stay >= row start)
    int offB = 4 * pt;                              // <= 496
    int offC = pE ? 496 : 4 * pt + 4;               // clamped (stay <= 496)
    float4 nA = *(const float4*)&yrow[offA];
    float4 nB = *(const float4*)&yrow[offB];
    float4 nC = *(const float4*)&yrow[offC];
#pragma unroll 1
    for (int c = 0; c < 8; c++) {
      float4 A = nA, B = nB, C = nC;
      const float* nxt = yrow + (c + 1) * 500;      // c=7 prefetch: in-ws garbage
      nA = *(const float4*)&nxt[offA];
      nB = *(const float4*)&nxt[offB];
      nC = *(const float4*)&nxt[offC];
      float sc = scs2[n * 64 + c], sh = scs2[n * 64 + 32 + c];  // uniform s_load
      float xr[12];
      xr[0] = A.x; xr[1] = A.y; xr[2] = A.z; xr[3] = A.w;
      xr[4] = B.x; xr[5] = B.y; xr[6] = B.z; xr[7] = B.w;
      xr[8] = C.x; xr[9] = C.y; xr[10] = C.z; xr[11] = C.w;
#pragma unroll
      for (int j = 0; j < 12; j++) xr[j] = fmaxf(xr[j] * sc + sh, 0.f);  // BN2+ReLU
      if (p0) { xr[1] = 0.f; xr[2] = 0.f; xr[3] = 0.f; }     // h2[-3..-1] = 0
      if (pE) { xr[8] = 0.f; xr[9] = 0.f; xr[10] = 0.f; }    // h2[500..502] = 0
#pragma unroll
      for (int k = 0; k < 7; k++) {
        float4 w0 = *(const float4*)&w3t[(c * 7 + k) * 16 + og * 8];
        float4 w1v = *(const float4*)&w3t[(c * 7 + k) * 16 + og * 8 + 4];
        v2f wp0, wp1, wp2, wp3;
        wp0.x = w0.x; wp0.y = w0.y;
        wp1.x = w0.z; wp1.y = w0.w;
        wp2.x = w1v.x; wp2.y = w1v.y;
        wp3.x = w1v.z; wp3.y = w1v.w;
#pragma unroll
        for (int r = 0; r < 4; r++) {
          v2f xs; xs.x = xr[r + k + 1]; xs.y = xr[r + k + 1];
          y3v[0][r] = pkfma(wp0, xs, y3v[0][r]);
          y3v[1][r] = pkfma(wp1, xs, y3v[1][r]);
          y3v[2][r] = pkfma(wp2, xs, y3v[2][r]);
          y3v[3][r] = pkfma(wp3, xs, y3v[3][r]);
        }
      }
    }
    long yb = (((long)n * BSZ + b) * 16 + og * 8) * 250 + 2 * pt;
#pragma unroll
    for (int oo = 0; oo < 4; oo++) {
      float2 vx, vy;
      vx.x = fmaxf(y3v[oo][0].x, y3v[oo][1].x);
      vx.y = fmaxf(y3v[oo][2].x, y3v[oo][3].x);
      *(float2*)&y3p[yb + (2 * oo) * 250] = vx;
      vy.x = fmaxf(y3v[oo][0].y, y3v[oo][1].y);
      vy.y = fmaxf(y3v[oo][2].y, y3v[oo][3].y);
      *(float2*)&y3p[yb + (2 * oo + 1) * 250] = vy;
    }
  }
  int lane = tid & 63, wv = tid >> 6;
#pragma unroll
  for (int o = 0; o < 8; o++) {
    float g0 = (o & 1) ? y3v[o >> 1][0].y : y3v[o >> 1][0].x;
    float g1 = (o & 1) ? y3v[o >> 1][1].y : y3v[o >> 1][1].x;
    float g2 = (o & 1) ? y3v[o >> 1][2].y : y3v[o >> 1][2].x;
    float g3 = (o & 1) ? y3v[o >> 1][3].y : y3v[o >> 1][3].x;
    float s = g0 + g1 + g2 + g3;
    float q = g0 * g0 + g1 * g1 + g2 * g2 + g3 * g3;
#pragma unroll
    for (int off = 32; off > 0; off >>= 1) {
      s += __shfl_down(s, off, 64);
      q += __shfl_down(q, off, 64);
    }
    if (lane == 0) { s_red[0][wv][o] = s; s_red[1][wv][o] = q; }
  }
  __syncthreads();
  if (tid < 16) {
    int og2 = tid >> 3, o = tid & 7;
    float s = s_red[0][2 * og2][o] + s_red[0][2 * og2 + 1][o];
    float q = s_red[1][2 * og2][o] + s_red[1][2 * og2 + 1][o];
    long slot = (long)n * BSZ + b;
    p3[slot * 32 + tid] = s;
    p3[slot * 32 + 16 + tid] = q;
  }
}

// ---------------------------------------------------------------------------
// F3: BN3 + ReLU + avg over pooled raw conv3 -> feat[b][n][16].
// grid: (1, B, N), block 256 (16 chans x 16 threads). SEPARATE kernel:
// R12 lesson — folding into 256-block graph_head collapses parallelism.
// ---------------------------------------------------------------------------
__global__ __launch_bounds__(256) void feat_apply(
    const float* __restrict__ y3p,
    const float* __restrict__ scs3,
    float* __restrict__ feat) {
  int tid = threadIdx.x, n = blockIdx.z, b = blockIdx.y;
  int ch = tid >> 4, s = tid & 15;
  const float* yb = y3p + (((long)n * BSZ + b) * 16 + ch) * 250;
  float sc = scs3[n * 64 + ch], sh = scs3[n * 64 + 32 + ch];
  float acc = 0.f;
  for (int j = s; j < 125; j += 16) {
    float2 v = *(const float2*)&yb[2 * j];
    acc += fmaxf(v.x * sc + sh, 0.f) + fmaxf(v.y * sc + sh, 0.f);
  }
#pragma unroll
  for (int off = 8; off > 0; off >>= 1) acc += __shfl_down(acc, off, 16);
  if (s == 0) feat[((long)b * NND + n) * 16 + ch] = acc * (1.0f / 250.f);
}

// ---------------------------------------------------------------------------
// Graph tail: adjacency (top-4 incl self) + 3 GCN layers + node-mean + MLP
// grid: (B), block: 256.
// ---------------------------------------------------------------------------
__global__ __launch_bounds__(256) void graph_head(
    const float* __restrict__ feat,
    const float* __restrict__ gw1, const float* __restrict__ gb1,
    const float* __restrict__ gw2, const float* __restrict__ gb2,
    const float* __restrict__ gw3, const float* __restrict__ gb3,
    const float* __restrict__ fw1, const float* __restrict__ fb1,
    const float* __restrict__ fw2, const float* __restrict__ fb2,
    float* __restrict__ out) {
  int b = blockIdx.x, tid = threadIdx.x;
  __shared__ float s_feat[NND][16];
  __shared__ float s_sq[NND];
  __shared__ float s_dist[NND][NND];
  __shared__ float s_adj[NND][NND];
  __shared__ float s_x[NND][128];
  __shared__ float s_t[NND][128];
  __shared__ float s_pool[128];
  __shared__ float s_h[64];
  for (int i = tid; i < NND * 16; i += 256) s_feat[i >> 4][i & 15] = feat[b * NND * 16 + i];
  __syncthreads();
  if (tid < NND) {
    float s = 0.f;
    for (int c = 0; c < 16; c++) s += s_feat[tid][c] * s_feat[tid][c];
    s_sq[tid] = s;
  }
  __syncthreads();
  for (int i = tid; i < NND * NND; i += 256) {
    int nn = i / NND, m = i % NND;
    float d = 0.f;
    for (int c = 0; c < 16; c++) d += s_feat[nn][c] * s_feat[m][c];
    s_dist[nn][m] = s_sq[nn] + s_sq[m] - 2.f * d;  // diagonal exactly 0
    s_adj[nn][m] = 0.f;
  }
  __syncthreads();
  if (tid < NND) {  // top-4 smallest, ties -> earliest index (matches top_k)
    unsigned used = 0;
    for (int j = 0; j < 4; j++) {
      float best = 3.4e38f; int bi = 0;
      for (int m = 0; m < NND; m++)
        if (!((used >> m) & 1u) && s_dist[tid][m] < best) { best = s_dist[tid][m]; bi = m; }
      used |= 1u << bi;
      s_adj[tid][bi] = 0.25f;
    }
  }
  __syncthreads();
  for (int i = tid; i < NND * 32; i += 256) {
    int nn = i / 32, f = i % 32;
    float a = 0.f;
    for (int c = 0; c < 16; c++) a += s_feat[nn][c] * gw1[c * 32 + f];
    s_t[nn][f] = a;
  }
  __syncthreads();
  for (int i = tid; i < NND * 32; i += 256) {
    int nn = i / 32, f = i % 32;
    float a = gb1[f];
    for (int m = 0; m < NND; m++) a += s_adj[nn][m] * s_t[m][f];
    s_x[nn][f] = fmaxf(a, 0.f);
  }
  __syncthreads();
  for (int i = tid; i < NND * 64; i += 256) {
    int nn = i / 64, f = i % 64;
    float a = 0.f;
    for (int c = 0; c < 32; c++) a += s_x[nn][c] * gw2[c * 64 + f];
    s_t[nn][f] = a;
  }
  __syncthreads();
  for (int i = tid; i < NND * 64; i += 256) {
    int nn = i / 64, f = i % 64;
    float a = gb2[f];
    for (int m = 0; m < NND; m++) a += s_adj[nn][m] * s_t[m][f];
    s_x[nn][f] = fmaxf(a, 0.f);
  }
  __syncthreads();
  for (int i = tid; i < NND * 128; i += 256) {
    int nn = i / 128, f = i % 128;
    float a = 0.f;
    for (int c = 0; c < 64; c++) a += s_x[nn][c] * gw3[c * 128 + f];
    s_t[nn][f] = a;
  }
  __syncthreads();
  for (int i = tid; i < NND * 128; i += 256) {
    int nn = i / 128, f = i % 128;
    float a = gb3[f];
    for (int m = 0; m < NND; m++) a += s_adj[nn][m] * s_t[m][f];
    s_x[nn][f] = fmaxf(a, 0.f);
  }
  __syncthreads();
  if (tid < 128) {
    float a = 0.f;
    for (int m = 0; m < NND; m++) a += s_x[m][tid];
    s_pool[tid] = a * (1.0f / (float)NND);
  }
  __syncthreads();
  if (tid < 64) {
    float a = fb1[tid];
    for (int c = 0; c < 128; c++) a += s_pool[c] * fw1[c * 64 + tid];
    s_h[tid] = a;
  }
  __syncthreads();
  if (tid < 4) {
    float a = fb2[tid];
    for (int c = 0; c < 64; c++) a += s_h[c] * fw2[c * 4 + tid];
    out[b * 4 + tid] = a;
  }
}

extern "C" void kernel_launch(void* const* d_in, const int* in_sizes, int n_in,
                              void* d_out, int out_size, void* d_ws, size_t ws_size,
                              hipStream_t stream) {
  (void)in_sizes; (void)n_in; (void)out_size; (void)ws_size;
  const float* x   = (const float*)d_in[0];
  const float* w1  = (const float*)d_in[1];
  const float* g1  = (const float*)d_in[2];
  const float* b1  = (const float*)d_in[3];
  const float* w2  = (const float*)d_in[4];
  const float* g2  = (const float*)d_in[5];
  const float* b2  = (const float*)d_in[6];
  const float* w3  = (const float*)d_in[7];
  const float* g3  = (const float*)d_in[8];
  const float* b3  = (const float*)d_in[9];
  const float* gw1 = (const float*)d_in[10];
  const float* gb1 = (const float*)d_in[11];
  const float* gw2 = (const float*)d_in[12];
  const float* gb2 = (const float*)d_in[13];
  const float* gw3 = (const float*)d_in[14];
  const float* gb3 = (const float*)d_in[15];
  const float* fw1 = (const float*)d_in[16];
  const float* fb1 = (const float*)d_in[17];
  const float* fw2 = (const float*)d_in[18];
  const float* fb2 = (const float*)d_in[19];

  float* ws = (float*)d_ws;
  const long Y2 = (long)NND * BSZ * 8 * 500;    // 22,528,000 floats
  const long Y3 = (long)NND * BSZ * 16 * 250;   // 22,528,000 floats
  float* y2p  = ws;
  float* y3p  = y2p + Y2;
  float* feat = y3p + Y3;                       // B*N*16 = 90,112
  float* scs1 = feat + (long)BSZ * NND * 16;
  float* scs2 = scs1 + NND * 64;
  float* scs3 = scs2 + NND * 64;
  float* p1   = scs3 + NND * 64;                // 22*512 slots * 8
  float* p2   = p1 + (long)NND * 512 * 8;       // 22*256 slots * 16
  float* p3   = p2 + (long)NND * 256 * 16;      // 22*256 slots * 32
  float* w2t  = p3 + (long)NND * 256 * 32;      // 224
  float* w3t  = w2t + 224;                      // 896
  // total ws ~= 181 MB (same budget as prior passing rounds)

  // S1: stats1 over x
  conv_statsR<1, 4, 2000, 256, 2, 4><<<dim3(2, BSZ, NND), dim3(256), 0, stream>>>(
      x, 2000, (long)NND * 2000, 0, w1, p1);
  // reduce1 (+ weight pre-transpose in block 0)
  stats_reduce<4, 512, 2000><<<dim3(NND), dim3(256), 0, stream>>>(
      p1, g1, b1, scs1, w2, w3, w2t, w3t);
  // conv1-apply (direct-x) + conv2 (pooled raw out) + stats2 partials
  fused1<<<dim3(1, BSZ, NND), dim3(256), 0, stream>>>(x, w1, scs1, w2t, y2p, p2);
  stats_reduce<8, 256, 1000><<<dim3(NND), dim3(256), 0, stream>>>(
      p2, g2, b2, scs2, nullptr, nullptr, nullptr, nullptr);
  // conv3 direct-from-global (BN2 in regs) -> pooled raw y3p + stats3
  fused2<<<dim3(1, BSZ, NND), dim3(256), 0, stream>>>(y2p, scs2, w3t, y3p, p3);
  stats_reduce<16, 256, 500><<<dim3(NND), dim3(256), 0, stream>>>(
      p3, g3, b3, scs3, nullptr, nullptr, nullptr, nullptr);
  // BN3 + ReLU + avg -> feat (separate 5632-block kernel; R12 lesson)
  feat_apply<<<dim3(1, BSZ, NND), dim3(256), 0, stream>>>(y3p, scs3, feat);
  // graph tail
  graph_head<<<dim3(BSZ), dim3(256), 0, stream>>>(
      feat, gw1, gb1, gw2, gb2, gw3, gb3, fw1, fb1, fw2, fb2, (float*)d_out);
}